// Round 13
// baseline (356.740 us; speedup 1.0000x reference)
//
#include <hip/hip_runtime.h>
#include <hip/hip_bf16.h>
#include <math.h>

#define Bc 2
#define Tc 1024
#define DMc 2048
#define NQc 16
#define NKVc 4
#define DHc 128
#define BLKc 32
#define STRIDEc 16
#define TOPNc 16
#define WINc 512
#define NREPc 4
#define NBc 63
#define SCALEc 0.08838834764831843f
#define KVP_LD 1280   // kvproj f32: 0..511 k_cmp | 512..1023 v_cmp | 1024..1071 gates | pad
#define KVB_LD 2048   // kvbf bf16: 0..511 k_slc | 1024..1535 k_win (v slices go to VT)

typedef unsigned short bf16_t;
typedef short s16x8 __attribute__((ext_vector_type(8)));
typedef float f32x4 __attribute__((ext_vector_type(4)));
typedef unsigned short u16x4 __attribute__((ext_vector_type(4)));
typedef unsigned int u32x4 __attribute__((ext_vector_type(4)));

__device__ __forceinline__ unsigned short f2bf(float f) {
  unsigned int u = __float_as_uint(f);
  u += 0x7fffu + ((u >> 16) & 1u);
  return (unsigned short)(u >> 16);
}
__device__ __forceinline__ float bf2f(unsigned short h) {
  return __uint_as_float((unsigned int)h << 16);
}
__device__ __forceinline__ float geluf(float x) {
  return 0.5f * x * (1.0f + erff(x * 0.7071067811865476f));
}
__device__ __forceinline__ void load_lds16(const void* g, void* l) {
  __builtin_amdgcn_global_load_lds(
      (const __attribute__((address_space(1))) void*)g,
      (__attribute__((address_space(3))) void*)l, 16, 0, 0);
}

// ---------- prep: x->hi/lo, wk_cmp->hi/lo ----------
__global__ void prep_kernel(const float* __restrict__ x, bf16_t* __restrict__ xbf,
                            bf16_t* __restrict__ xlo,
                            const float* __restrict__ wk_cmp,
                            bf16_t* __restrict__ Wk_hi, bf16_t* __restrict__ Wk_lo) {
  size_t gid = (size_t)blockIdx.x * 256 + threadIdx.x;  // exact: 5242880/256 = 20480
  if (gid < 4194304) {
    float f = x[gid];
    bf16_t h = f2bf(f);
    xbf[gid] = h;
    xlo[gid] = f2bf(f - bf2f(h));
  } else {
    size_t i = gid - 4194304;
    float f = wk_cmp[i];
    bf16_t h = f2bf(f);
    Wk_hi[i] = h;
    Wk_lo[i] = f2bf(f - bf2f(h));
  }
}

// ---------- concat weights rows 512..3199 into bf16 Wcat ----------
__global__ void build_wcat(
    const float* __restrict__ wv_cmp, const float* __restrict__ wk_slc,
    const float* __restrict__ wv_slc, const float* __restrict__ wk_win,
    const float* __restrict__ wv_win, const float* __restrict__ gate_w,
    const float* __restrict__ gate_b, bf16_t* __restrict__ Wcat,
    float* __restrict__ bias_cat) {
  size_t i = (size_t)blockIdx.x * 256 + threadIdx.x;  // exact: 2688*2048/256
  int rr = (int)(i >> 11), c = (int)(i & 2047);
  int r = rr + 512;
  float v = 0.f;
  if (r < 3072) {
    int blk = r >> 9;  // 1..5
    size_t o = (size_t)(r & 511) * 2048 + c;
    if (blk == 1) v = wv_cmp[o];
    else if (blk == 2) v = wk_slc[o];
    else if (blk == 3) v = wv_slc[o];
    else if (blk == 4) v = wk_win[o];
    else v = wv_win[o];
  } else if (r < 3120) {
    v = gate_w[(size_t)(r - 3072) * 2048 + c];
  }
  Wcat[i] = f2bf(v);
  if (c == 0) bias_cat[r] = (r >= 3072 && r < 3120) ? gate_b[r - 3072] : 0.f;
}

// ---------- hi/lo split-bf16 MFMA GEMM for k_cmp, BM=128 BN=64, split-K x2 ----------
__global__ __launch_bounds__(256) void gemm_prec(
    const bf16_t* __restrict__ A, const bf16_t* __restrict__ Alo,
    const bf16_t* __restrict__ Bw, const bf16_t* __restrict__ Blo,
    float* __restrict__ part) {
  __shared__ bf16_t As[2 * 128 * 32];
  __shared__ bf16_t Bs[2 * 64 * 32];
  const int z = blockIdx.z;
  const int bm = blockIdx.y * 128, bnw = blockIdx.x * 64;
  const int tid = threadIdx.x, lane = tid & 63, w = tid >> 6;
  const int wr = (w >> 1) * 64, wc = (w & 1) * 32;
  const int kbase = z * 1024;

  f32x4 acc[4][2];
#pragma unroll
  for (int i = 0; i < 4; ++i)
#pragma unroll
    for (int j = 0; j < 2; ++j) acc[i][j] = 0.f;

  const int srow = lane >> 2;
  const int sslot = lane & 3;

  for (int k0 = kbase; k0 < kbase + 1024; k0 += 32) {
    __syncthreads();
#pragma unroll
    for (int j = 0; j < 2; ++j) {  // A hi/lo: 128 rows each
      int rb = w * 32 + j * 16;
      int row = rb + srow;
      int slot = sslot ^ ((row >> 1) & 3);
      load_lds16(A + (size_t)(bm + row) * 2048 + k0 + slot * 8, &As[rb * 32]);
      load_lds16(Alo + (size_t)(bm + row) * 2048 + k0 + slot * 8, &As[4096 + rb * 32]);
    }
    {  // B hi/lo: 64 rows each, 1 inst/wave each
      int rb = w * 16;
      int row = rb + srow;
      int slot = sslot ^ ((row >> 1) & 3);
      load_lds16(Bw + (size_t)(bnw + row) * 2048 + k0 + slot * 8, &Bs[rb * 32]);
      load_lds16(Blo + (size_t)(bnw + row) * 2048 + k0 + slot * 8, &Bs[2048 + rb * 32]);
    }
    __syncthreads();

    s16x8 af[4], afl[4], bfr[2], bfl[2];
#pragma unroll
    for (int i = 0; i < 4; ++i) {
      int ar = wr + i * 16 + (lane & 15);
      int as = ((lane >> 4) ^ ((ar >> 1) & 3)) * 8;
      af[i] = *(const s16x8*)&As[ar * 32 + as];
      afl[i] = *(const s16x8*)&As[4096 + ar * 32 + as];
    }
#pragma unroll
    for (int j = 0; j < 2; ++j) {
      int br = wc + j * 16 + (lane & 15);
      int bs = ((lane >> 4) ^ ((br >> 1) & 3)) * 8;
      bfr[j] = *(const s16x8*)&Bs[br * 32 + bs];
      bfl[j] = *(const s16x8*)&Bs[2048 + br * 32 + bs];
    }
#pragma unroll
    for (int i = 0; i < 4; ++i)
#pragma unroll
      for (int j = 0; j < 2; ++j) {
        acc[i][j] = __builtin_amdgcn_mfma_f32_16x16x32_bf16(afl[i], bfr[j], acc[i][j], 0, 0, 0);
        acc[i][j] = __builtin_amdgcn_mfma_f32_16x16x32_bf16(af[i], bfl[j], acc[i][j], 0, 0, 0);
        acc[i][j] = __builtin_amdgcn_mfma_f32_16x16x32_bf16(af[i], bfr[j], acc[i][j], 0, 0, 0);
      }
  }

  float* pz = part + (size_t)z * 1048576;
#pragma unroll
  for (int i = 0; i < 4; ++i) {
    int row = bm + wr + i * 16 + ((lane >> 4) << 2);
#pragma unroll
    for (int j = 0; j < 2; ++j) {
      int col = bnw + wc + j * 16 + (lane & 15);
#pragma unroll
      for (int r = 0; r < 4; ++r)
        pz[(size_t)(row + r) * 512 + col] = acc[i][j][r];
    }
  }
}

// ---------- reduce 2 k_cmp partials + RoPE -> kvproj cols 0..511 ----------
__global__ void rope_k_fused2(const float* __restrict__ part,
                              float* __restrict__ kvproj) {
  int blk = blockIdx.x;  // (b*T+t)*KV+kv
  int kv = blk & 3;
  int t = (blk >> 2) & (Tc - 1);
  int b = blk >> 12;
  int d = threadIdx.x;  // 0..63
  size_t base = (size_t)(b * Tc + t) * 512 + kv * 128;
  float x1 = part[base + d] + part[1048576 + base + d];
  float x2 = part[base + d + 64] + part[1048576 + base + d + 64];
  float inv = powf(10000.f, -(float)d * (1.f / 64.f));
  float ang = (float)t * inv;
  float s, c;
  sincosf(ang, &s, &c);
  float* p = kvproj + (size_t)(b * Tc + t) * KVP_LD + kv * 128;
  p[d] = x1 * c - x2 * s;
  p[d + 64] = x1 * s + x2 * c;
}

// ---------- bf16 MFMA GEMM: cols 512..3199, BM=128 BN=64 ----------
__global__ __launch_bounds__(256) void gemm_mfma(
    const bf16_t* __restrict__ A, int lda,
    const bf16_t* __restrict__ Bw, int ldb,
    float* __restrict__ kvproj, bf16_t* __restrict__ kvbf,
    bf16_t* __restrict__ VT, const float* __restrict__ bias, int K) {
  __shared__ bf16_t As[128 * 32];
  __shared__ bf16_t Bs[64 * 32];
  const int bm = blockIdx.y * 128, bnw = blockIdx.x * 64, bn = 512 + bnw;
  const int tid = threadIdx.x, lane = tid & 63, w = tid >> 6;
  const int wr = (w >> 1) * 64, wc = (w & 1) * 32;

  f32x4 acc[4][2];
#pragma unroll
  for (int i = 0; i < 4; ++i)
#pragma unroll
    for (int j = 0; j < 2; ++j) acc[i][j] = 0.f;

  const int srow = lane >> 2;
  const int sslot = lane & 3;

  for (int k0 = 0; k0 < K; k0 += 32) {
    __syncthreads();
#pragma unroll
    for (int j = 0; j < 2; ++j) {
      int rb = w * 32 + j * 16;
      int row = rb + srow;
      int slot = sslot ^ ((row >> 1) & 3);
      load_lds16(A + (size_t)(bm + row) * lda + k0 + slot * 8, &As[rb * 32]);
    }
    {
      int rb = w * 16;
      int row = rb + srow;
      int slot = sslot ^ ((row >> 1) & 3);
      load_lds16(Bw + (size_t)(bnw + row) * ldb + k0 + slot * 8, &Bs[rb * 32]);
    }
    __syncthreads();

    s16x8 af[4], bfr[2];
#pragma unroll
    for (int i = 0; i < 4; ++i) {
      int ar = wr + i * 16 + (lane & 15);
      int as = ((lane >> 4) ^ ((ar >> 1) & 3)) * 8;
      af[i] = *(const s16x8*)&As[ar * 32 + as];
    }
#pragma unroll
    for (int j = 0; j < 2; ++j) {
      int br = wc + j * 16 + (lane & 15);
      int bs = ((lane >> 4) ^ ((br >> 1) & 3)) * 8;
      bfr[j] = *(const s16x8*)&Bs[br * 32 + bs];
    }
#pragma unroll
    for (int i = 0; i < 4; ++i)
#pragma unroll
      for (int j = 0; j < 2; ++j)
        acc[i][j] = __builtin_amdgcn_mfma_f32_16x16x32_bf16(af[i], bfr[j], acc[i][j], 0, 0, 0);
  }

#pragma unroll
  for (int i = 0; i < 4; ++i) {
    int row = bm + wr + i * 16 + ((lane >> 4) << 2);
#pragma unroll
    for (int j = 0; j < 2; ++j) {
      int col = bn + wc + j * 16 + (lane & 15);
      float bv = bias[col];
      float vals[4];
#pragma unroll
      for (int r = 0; r < 4; ++r) vals[r] = acc[i][j][r] + bv;
      if (col < 1024) {  // v_cmp -> f32 kvproj
#pragma unroll
        for (int r = 0; r < 4; ++r)
          kvproj[(size_t)(row + r) * KVP_LD + col] = vals[r];
      } else if (col < 3072) {
        int cc = col - 1024;
        int region = cc >> 9;  // 0 k_slc, 1 v_slc, 2 k_win, 3 v_win
        if ((region & 1) == 0) {
#pragma unroll
          for (int r = 0; r < 4; ++r)
            kvbf[(size_t)(row + r) * KVB_LD + cc] = f2bf(vals[r]);
        } else {
          int mode = region >> 1;
          int kv = (cc >> 7) & 3, d = cc & 127;
          int b = row >> 10;
          u16x4 w4;
#pragma unroll
          for (int r = 0; r < 4; ++r) w4[r] = f2bf(vals[r]);
          *(u16x4*)(VT + (size_t)((b * 4 + kv) * 2 + mode) * 131072 +
                    d * 1024 + (row & 1023)) = w4;
        }
      } else {
#pragma unroll
        for (int r = 0; r < 4; ++r)
          kvproj[(size_t)(row + r) * KVP_LD + (col - 2048)] =
              1.f / (1.f + __expf(-vals[r]));
      }
    }
  }
}

// ---------- RoPE in place on kvbf K slices (bf16) ----------
__global__ void rope_bf(bf16_t* __restrict__ kvbf) {
  int blk = blockIdx.x;
  int coloff = blockIdx.y << 10;  // 0 (slc K) or 1024 (win K)
  int kv = blk & 3;
  int t = (blk >> 2) & (Tc - 1);
  int b = blk >> 12;
  bf16_t* p = kvbf + (size_t)(b * Tc + t) * KVB_LD + coloff + kv * 128;
  int d = threadIdx.x;
  float inv = powf(10000.f, -(float)d * (1.f / 64.f));
  float ang = (float)t * inv;
  float s, c;
  sincosf(ang, &s, &c);
  float x1 = bf2f(p[d]), x2 = bf2f(p[d + 64]);
  p[d] = f2bf(x1 * c - x2 * s);
  p[d + 64] = f2bf(x1 * s + x2 * c);
}

// ---------- compress layer1: gathered-A GEMM, split-K x16, k&v merged ----------
__global__ __launch_bounds__(256) void gemm_cmp1(
    const float* __restrict__ kvproj,
    const float* __restrict__ ck1_w, const float* __restrict__ cv1_w,
    float* __restrict__ hk_part, float* __restrict__ hv_part) {
  __shared__ float As[16][68];
  __shared__ float Ws[16][68];
  const int zz = blockIdx.z;
  const bool isv = zz >= 16;
  const int z = zz & 15;
  const int coloff = isv ? 512 : 0;
  const float* W = isv ? cv1_w : ck1_w;
  float* Cpart = isv ? hv_part : hk_part;
  const int bm = blockIdx.y * 64, bn = blockIdx.x * 64;
  const int tid = threadIdx.x;
  const int tx = tid & 15, ty = tid >> 4;
  float acc[4][4] = {{0.f}};
  for (int k0 = z * 256; k0 < z * 256 + 256; k0 += 16) {
#pragma unroll
    for (int i0 = 0; i0 < 4; ++i0) {
      int i = tid + i0 * 256;
      int m = i >> 4, kk = i & 15;
      int gm = bm + m;
      float av = 0.f;
      if (gm < 504) {
        int b = gm / 252, rem = gm % 252;
        int n = rem >> 2, kv = rem & 3;
        int f = k0 + kk;
        int j = f >> 7, d = f & 127;
        av = kvproj[(size_t)(b * Tc + n * 16 + j) * KVP_LD + coloff + kv * 128 + d];
      }
      As[kk][m] = av;
      Ws[kk][m] = W[(size_t)(bn + m) * 4096 + (k0 + kk)];
    }
    __syncthreads();
#pragma unroll
    for (int kk = 0; kk < 16; ++kk) {
      float4 a4 = *reinterpret_cast<const float4*>(&As[kk][ty * 4]);
      float4 w4 = *reinterpret_cast<const float4*>(&Ws[kk][tx * 4]);
      float av[4] = {a4.x, a4.y, a4.z, a4.w};
      float wv[4] = {w4.x, w4.y, w4.z, w4.w};
#pragma unroll
      for (int i = 0; i < 4; ++i)
#pragma unroll
        for (int j = 0; j < 4; ++j) acc[i][j] = fmaf(av[i], wv[j], acc[i][j]);
    }
    __syncthreads();
  }
#pragma unroll
  for (int i = 0; i < 4; ++i) {
    int m = bm + ty * 4 + i;
    if (m >= 504) continue;
#pragma unroll
    for (int j = 0; j < 4; ++j)
      Cpart[(size_t)z * 64512 + (size_t)m * 128 + bn + tx * 4 + j] = acc[i][j];
  }
}

// ---------- bias_adj[o] = b1[o] + block_pos_flat . w1[o,:] ----------
__global__ void bias_adj_kernel(const float* __restrict__ bp,
                                const float* __restrict__ w1k,
                                const float* __restrict__ b1k,
                                const float* __restrict__ w1v,
                                const float* __restrict__ b1v,
                                float* __restrict__ outk,
                                float* __restrict__ outv) {
  __shared__ float red[4];
  const int o = blockIdx.x;
  const float* w1 = blockIdx.y ? w1v : w1k;
  float s = 0.f;
  for (int i = threadIdx.x; i < 4096; i += 256)
    s += bp[i] * w1[(size_t)o * 4096 + i];
#pragma unroll
  for (int off = 32; off; off >>= 1) s += __shfl_xor(s, off);
  if ((threadIdx.x & 63) == 0) red[threadIdx.x >> 6] = s;
  __syncthreads();
  if (threadIdx.x == 0) {
    float t = red[0] + red[1] + red[2] + red[3];
    if (blockIdx.y) outv[o] = t + b1v[o];
    else outk[o] = t + b1k[o];
  }
}

// ---------- reduce 16 partials + bias + gelu, k&v merged ----------
__global__ void reduce_gelu(const float* __restrict__ hk_part,
                            const float* __restrict__ hv_part,
                            const float* __restrict__ bias_k,
                            const float* __restrict__ bias_v,
                            float* __restrict__ hk, float* __restrict__ hv) {
  int gi = blockIdx.x * 256 + threadIdx.x;  // exact: 2*64512/256
  const bool isv = gi >= 64512;
  int i = isv ? gi - 64512 : gi;
  const float* parts = isv ? hv_part : hk_part;
  float s = (isv ? bias_v : bias_k)[i & 127];
#pragma unroll
  for (int z = 0; z < 16; ++z) s += parts[z * 64512 + i];
  (isv ? hv : hk)[i] = geluf(s);
}

// ---------- compress layer2, k&v merged ----------
__global__ __launch_bounds__(256) void gemm_l2(
    const float* __restrict__ hk, const float* __restrict__ w2k,
    const float* __restrict__ b2k, const float* __restrict__ hv,
    const float* __restrict__ w2v, const float* __restrict__ b2v,
    float* __restrict__ k_sum, float* __restrict__ v_sum) {
  __shared__ float As[16][68];
  __shared__ float Ws[16][68];
  const bool isv = blockIdx.z != 0;
  const float* A = isv ? hv : hk;
  const float* W = isv ? w2v : w2k;
  const float* bias = isv ? b2v : b2k;
  float* C = isv ? v_sum : k_sum;
  const int bm = blockIdx.y * 64, bn = blockIdx.x * 64;
  const int tid = threadIdx.x;
  const int tx = tid & 15, ty = tid >> 4;
  float acc[4][4] = {{0.f}};
  for (int k0 = 0; k0 < 128; k0 += 16) {
#pragma unroll
    for (int i0 = 0; i0 < 4; ++i0) {
      int i = tid + i0 * 256;
      int m = i >> 4, kk = i & 15;
      int gm = bm + m;
      As[kk][m] = (gm < 504) ? A[(size_t)gm * 128 + (k0 + kk)] : 0.f;
      Ws[kk][m] = W[(size_t)(bn + m) * 128 + (k0 + kk)];
    }
    __syncthreads();
#pragma unroll
    for (int kk = 0; kk < 16; ++kk) {
      float4 a4 = *reinterpret_cast<const float4*>(&As[kk][ty * 4]);
      float4 w4 = *reinterpret_cast<const float4*>(&Ws[kk][tx * 4]);
      float av[4] = {a4.x, a4.y, a4.z, a4.w};
      float wv[4] = {w4.x, w4.y, w4.z, w4.w};
#pragma unroll
      for (int i = 0; i < 4; ++i)
#pragma unroll
        for (int j = 0; j < 4; ++j) acc[i][j] = fmaf(av[i], wv[j], acc[i][j]);
    }
    __syncthreads();
  }
#pragma unroll
  for (int i = 0; i < 4; ++i) {
    int m = bm + ty * 4 + i;
    if (m >= 504) continue;
#pragma unroll
    for (int j = 0; j < 4; ++j)
      C[(size_t)m * 128 + bn + tx * 4 + j] = acc[i][j] + bias[bn + tx * 4 + j];
  }
}

// ---------- compressed attention + top-k: 4 query tokens per wg ----------
__global__ __launch_bounds__(256) void cmp_attn(
    const float* __restrict__ q, const float* __restrict__ k_sum,
    const float* __restrict__ v_sum, const float* __restrict__ kvproj,
    float* __restrict__ out, unsigned long long* __restrict__ sel) {
  __shared__ __align__(16) float q_s[4][4][128];
  __shared__ __align__(16) float ks[NBc * 128];
  __shared__ float p_s[4][4][64];

  const int wg = blockIdx.x;  // (b*4+kv)*256 + tq
  const int tq = wg & 255;
  const int kv = (wg >> 8) & 3;
  const int b = wg >> 10;
  const int t0 = tq * 4;
  const int tid = threadIdx.x;
  const int lane = tid & 63;
  const int g = tid >> 6;

  for (int i = tid; i < 2048; i += 256) {
    int gg = i >> 9, r = (i >> 7) & 3, d = i & 127;
    q_s[gg][r][d] = q[(((size_t)b * NQc + gg * NKVc + kv) * Tc + t0 + r) * 128 + d];
  }
  {
    const float* kbase = k_sum + (size_t)(b * 252 + kv) * 128;
    for (int i = tid; i < NBc * 32; i += 256) {
      int n = i >> 5, s = i & 31;
      f32x4 v4 = *(const f32x4*)(kbase + (size_t)n * 512 + s * 4);
      *(f32x4*)&ks[n * 128 + ((s ^ (n & 7)) << 2)] = v4;
    }
  }
  __syncthreads();

  float acc[4] = {0.f, 0.f, 0.f, 0.f};
  {
    const int lrow = (lane < 63) ? lane : 62;
    const int lx = lrow & 7;
#pragma unroll
    for (int s = 0; s < 32; ++s) {
      f32x4 k4 = *(const f32x4*)&ks[lrow * 128 + ((s ^ lx) << 2)];
#pragma unroll
      for (int r = 0; r < 4; ++r) {
        f32x4 q4 = *(const f32x4*)&q_s[g][r][s * 4];
        acc[r] = fmaf(q4[0], k4[0], acc[r]);
        acc[r] = fmaf(q4[1], k4[1], acc[r]);
        acc[r] = fmaf(q4[2], k4[2], acc[r]);
        acc[r] = fmaf(q4[3], k4[3], acc[r]);
      }
    }
  }
#pragma unroll
  for (int r = 0; r < 4; ++r) {
    const int t = t0 + r;
    const int nvalid = min(t / STRIDEc + 1, NBc);
    const bool valid = (lane < nvalid);
    float sval = valid ? acc[r] * SCALEc : -INFINITY;
    float m = sval;
#pragma unroll
    for (int off = 32; off; off >>= 1) m = fmaxf(m, __shfl_xor(m, off));
    float e = valid ? __expf(sval - m) : 0.f;
    float l = e;
#pragma unroll
    for (int off = 32; off; off >>= 1) l += __shfl_xor(l, off);
    p_s[g][r][lane] = e / fmaxf(l, 1e-9f);
  }
  __syncthreads();

  {  // top-k: wave g handles row r=g
    float v = p_s[0][g][lane] + p_s[1][g][lane] + p_s[2][g][lane] + p_s[3][g][lane];
    if (lane >= NBc) v = -1.f;
    unsigned long long mask = 0ull;
    for (int it = 0; it < TOPNc; ++it) {
      float mx = v;
#pragma unroll
      for (int off = 32; off; off >>= 1) mx = fmaxf(mx, __shfl_xor(mx, off));
      unsigned long long ball = __ballot(v == mx);
      int sl = __ffsll(ball) - 1;
      mask |= 1ull << sl;
      if (lane == sl) v = -1.f;
    }
    if (lane == 0) sel[(((size_t)b * NKVc + kv) << 10) + t0 + g] = mask;
  }
  {
    const float* vbase = v_sum + (size_t)(b * 252 + kv) * 128;
    for (int i = tid; i < NBc * 32; i += 256) {
      int n = i >> 5, s = i & 31;
      f32x4 v4 = *(const f32x4*)(vbase + (size_t)n * 512 + s * 4);
      *(f32x4*)&ks[n * 128 + ((s ^ (n & 7)) << 2)] = v4;
    }
  }
  __syncthreads();

  const int h = g * NKVc + kv;
  float ox[4] = {0.f, 0.f, 0.f, 0.f}, oy[4] = {0.f, 0.f, 0.f, 0.f};
  const int slotd = lane >> 1, wi = (lane & 1) * 2;
  const int nvmax = min((t0 + 3) / STRIDEc + 1, NBc);
  for (int n = 0; n < nvmax; ++n) {
    const float* vp = &ks[n * 128 + (((slotd ^ (n & 7)) << 2) | wi)];
    const float vx = vp[0], vy = vp[1];
#pragma unroll
    for (int r = 0; r < 4; ++r) {
      float pn = p_s[g][r][n];
      ox[r] = fmaf(pn, vx, ox[r]);
      oy[r] = fmaf(pn, vy, oy[r]);
    }
  }
#pragma unroll
  for (int r = 0; r < 4; ++r) {
    const int t = t0 + r;
    const float g0 = kvproj[(size_t)(b * Tc + t) * KVP_LD + 1024 + h * 3];
    size_t obase = ((size_t)(b * NQc + h) * Tc + t) * 128 + lane * 2;
    *(float2*)&out[obase] = make_float2(g0 * ox[r], g0 * oy[r]);
  }
}

// ---------- merged MFMA flash-tile attention: QBLK=16, 4 waves, chunk=32 ----------
// grid 1024 (4 wg/CU); wgi: b=bit0, kv=bits1-2, Y=bits3-8, mode=bit9;
// tt = mode ? Y : 63-Y (mode anti-correlated across dispatch halves).
__global__ __launch_bounds__(256, 5) void sparse_attn_mfma(
    const float* __restrict__ q, const bf16_t* __restrict__ kvbf,
    const bf16_t* __restrict__ VT, const float* __restrict__ kvproj,
    const unsigned long long* __restrict__ sel,
    float* __restrict__ out, float* __restrict__ out2) {
  __shared__ bf16_t KsB[2][32 * 128];   // [s][d], 256B rows, swz ^((s&7)<<4)
  __shared__ bf16_t VtB[2][128 * 32];   // d-pairs per 128B row: byte=(d>>1)*128+(d&1)*64+slot*16, swz ^(((d>>1)&7)<<4)

  const int wgi = blockIdx.x;
  const int b = wgi & 1;
  const int kv = (wgi >> 1) & 3;
  const int Y = (wgi >> 3) & 63;
  const int mode = (wgi >> 9) & 1;
  const int tt = mode ? Y : 63 - Y;
  const int t0 = tt * 16;
  const int tid = threadIdx.x, lane = tid & 63;
  const int g = tid >> 6;  // wave = head
  const int h = g * NKVc + kv;
  const int lr = lane >> 4;
  const int lc = lane & 15;
  const int tL = t0 + lc;  // this lane's softmax column (query row)

  s16x8 aq[4];
  {
    const float* qrow = q + (((size_t)(b * NQc + h) * Tc) + tL) * 128;
#pragma unroll
    for (int ks = 0; ks < 4; ++ks) {
      f32x4 lo = *(const f32x4*)(qrow + ks * 32 + lr * 8);
      f32x4 hi = *(const f32x4*)(qrow + ks * 32 + lr * 8 + 4);
      s16x8 v;
#pragma unroll
      for (int e = 0; e < 4; ++e) {
        v[e] = (short)f2bf(lo[e]);
        v[e + 4] = (short)f2bf(hi[e]);
      }
      aq[ks] = v;
    }
  }

  unsigned long long hm = ~0ull;
  unsigned long long um = ~0ull;
  int c0;
  const int c1 = (t0 + 15) >> 5;
  const unsigned long long* sb = sel + ((size_t)(b * NKVc + kv) << 10);
  if (mode == 0) {
    unsigned long long bm = sb[tL];
    hm = bm | (bm << 1);
    // wg-uniform union over the 16 rows (sel is head-independent)
    unsigned long long uu = 0ull;
    if (lane < 16) {
      unsigned long long b2 = sb[t0 + lane];
      uu = b2 | (b2 << 1);
    }
#pragma unroll
    for (int off = 32; off; off >>= 1) uu |= __shfl_xor(uu, off);
    um = uu;
    c0 = (__ffsll(um) - 1) >> 1;
  } else {
    int lo = t0 - (WINc - 1);
    c0 = (lo > 0 ? lo : 0) >> 5;
  }

  float run_m = -INFINITY, run_l = 0.f;
  f32x4 acc_o[8];  // O[t=t0+lr*4+r][d=jo*16+lc]
#pragma unroll
  for (int j = 0; j < 8; ++j) acc_o[j] = 0.f;

  const bf16_t* kb = kvbf + (mode << 10) + kv * 128;
  const bf16_t* vt = VT + (size_t)((b * 4 + kv) * 2 + mode) * 131072;
  const size_t rbase = (size_t)b * Tc;

  auto STAGE = [&](int bufi, int c) {
    const int s0 = c * 32;
#pragma unroll
    for (int p = 0; p < 2; ++p) {  // K: 32 rows x 16 slots of 16B = 512 slots
      int pos = p * 256 + tid;
      int s = pos >> 4, sl = pos & 15;
      int slot = sl ^ (s & 7);
      load_lds16(kb + (rbase + s0 + s) * KVB_LD + slot * 8,
                 (char*)&KsB[bufi][0] + (p * 256 + g * 64) * 16);
    }
#pragma unroll
    for (int p = 0; p < 2; ++p) {  // V^T: 512 slots; decode physical pos -> (d,slot)
      int pos = p * 256 + tid;
      int u = pos >> 3;                       // 128B LDS row
      int val = ((pos & 7) * 16) ^ ((u & 7) << 4);
      int d = u * 2 + (val >> 6);
      int slot = (val >> 4) & 3;
      load_lds16(vt + (size_t)d * 1024 + s0 + slot * 8,
                 (char*)&VtB[bufi][0] + (p * 256 + g * 64) * 16);
    }
  };

  int c = c0;
  STAGE(0, c);
  int buf = 0;
  while (true) {
    int cn = c + 1;
    if (mode == 0)
      while (cn <= c1 && ((um >> (2 * cn)) & 3ull) == 0ull) ++cn;
    __syncthreads();  // vmcnt(0) drained: buf staged, prev buf free
    if (cn <= c1) STAGE(buf ^ 1, cn);

    const int s0 = c * 32;
    const char* KsP = (const char*)&KsB[buf][0];
    const char* VtP = (const char*)&VtB[buf][0];

    // S^T = mfma(K, Q): lane holds S[s0+j*16+lr*4+r][tL], j=0..1
    f32x4 accs[2];
#pragma unroll
    for (int j = 0; j < 2; ++j) accs[j] = 0.f;
    __builtin_amdgcn_s_setprio(1);
#pragma unroll
    for (int ks = 0; ks < 4; ++ks) {
      s16x8 bk[2];
#pragma unroll
      for (int j = 0; j < 2; ++j) {
        int sB = j * 16 + lc;
        bk[j] = *(const s16x8*)(KsP +
                                ((sB * 256 + (ks * 4 + lr) * 16) ^ ((sB & 7) << 4)));
      }
#pragma unroll
      for (int j = 0; j < 2; ++j)
        accs[j] = __builtin_amdgcn_mfma_f32_16x16x32_bf16(bk[j], aq[ks], accs[j], 0, 0, 0);
    }
    __builtin_amdgcn_s_setprio(0);

    float ev[2][4];
    float mx = -INFINITY;
#pragma unroll
    for (int j = 0; j < 2; ++j)
#pragma unroll
      for (int r = 0; r < 4; ++r) {
        int s = s0 + j * 16 + lr * 4 + r;
        bool att;
        if (mode == 0) att = (s <= tL) && ((hm >> (s >> 4)) & 1ull);
        else att = (s <= tL) && (tL - s < WINc);
        float sv = att ? accs[j][r] * SCALEc : -INFINITY;
        ev[j][r] = sv;
        mx = fmaxf(mx, sv);
      }
    mx = fmaxf(mx, __shfl_xor(mx, 16));
    mx = fmaxf(mx, __shfl_xor(mx, 32));
    const bool defer = __all(mx <= run_m + 8.f);
    float nm = run_m;
    if (!defer) {
      nm = fmaxf(run_m, mx);
      const float resc = (run_m == -INFINITY) ? 0.f : __expf(run_m - nm);
      float rs[4];
#pragma unroll
      for (int r = 0; r < 4; ++r) rs[r] = __shfl(resc, lr * 16 + lr * 4 + r);
#pragma unroll
      for (int jo = 0; jo < 8; ++jo)
#pragma unroll
        for (int r = 0; r < 4; ++r) acc_o[jo][r] *= rs[r];
      run_l *= resc;
      run_m = nm;
    }
    float cl = 0.f;
#pragma unroll
    for (int j = 0; j < 2; ++j)
#pragma unroll
      for (int r = 0; r < 4; ++r) {
        float e = (ev[j][r] == -INFINITY) ? 0.f : __expf(ev[j][r] - nm);
        ev[j][r] = e;
        cl += e;
      }
    cl += __shfl_xor(cl, 16);
    cl += __shfl_xor(cl, 32);
    run_l += cl;

    unsigned int pw[2][2];
#pragma unroll
    for (int j = 0; j < 2; ++j) {
      pw[j][0] = ((unsigned int)f2bf(ev[j][1]) << 16) | f2bf(ev[j][0]);
      pw[j][1] = ((unsigned int)f2bf(ev[j][3]) << 16) | f2bf(ev[j][2]);
    }

    // PV A-fragment: ap elem e = P[s0+lr*8+e][tL]
    s16x8 ap;
    {
      u32x4 words;
#pragma unroll
      for (int w = 0; w < 4; ++w) {
        int src = ((lr & 1) * 2 + (w >> 1)) * 16 + lc;
        unsigned int a0 = __shfl((int)pw[0][w & 1], src);
        unsigned int a1 = __shfl((int)pw[1][w & 1], src);
        words[w] = (lr >> 1) ? a1 : a0;
      }
      ap = __builtin_bit_cast(s16x8, words);
    }

    __builtin_amdgcn_s_setprio(1);
#pragma unroll
    for (int jo = 0; jo < 8; ++jo) {
      int d = jo * 16 + lc;
      int byte = ((d >> 1) * 128 + (d & 1) * 64 + lr * 16) ^ (((d >> 1) & 7) << 4);
      s16x8 bv = *(const s16x8*)(VtP + byte);
      acc_o[jo] = __builtin_amdgcn_mfma_f32_16x16x32_bf16(ap, bv, acc_o[jo], 0, 0, 0);
    }
    __builtin_amdgcn_s_setprio(0);

    if (cn > c1) break;
    buf ^= 1;
    c = cn;
  }

  float rl[4];
#pragma unroll
  for (int r = 0; r < 4; ++r) rl[r] = __shfl(run_l, lr * 16 + lr * 4 + r);
#pragma unroll
  for (int r = 0; r < 4; ++r) {
    const int t = t0 + lr * 4 + r;
    const float gg = kvproj[(rbase + t) * KVP_LD + 1024 + h * 3 + 1 + mode];
    const float sc = gg / fmaxf(rl[r], 1e-9f);
    const size_t ob = ((size_t)(b * NQc + h) * Tc + t) * 128;
#pragma unroll
    for (int jo = 0; jo < 8; ++jo) {
      size_t oi = ob + jo * 16 + lc;
      float v = acc_o[jo][r] * sc;
      if (mode == 0) out[oi] += v;
      else out2[oi] = v;
    }
  }
}

// ---------- out += out2 ----------
__global__ void add_out(float* __restrict__ out, const float* __restrict__ out2) {
  size_t i = (size_t)blockIdx.x * 256 + threadIdx.x;  // exact: 4194304/256
  out[i] += out2[i];
}

extern "C" void kernel_launch(void* const* d_in, const int* in_sizes, int n_in,
                              void* d_out, int out_size, void* d_ws, size_t ws_size,
                              hipStream_t stream) {
  const float* x = (const float*)d_in[0];
  const float* q = (const float*)d_in[1];
  const float* gate_w = (const float*)d_in[2];
  const float* gate_b = (const float*)d_in[3];
  const float* wk_cmp = (const float*)d_in[4];
  const float* wv_cmp = (const float*)d_in[5];
  const float* wk_slc = (const float*)d_in[6];
  const float* wv_slc = (const float*)d_in[7];
  const float* wk_win = (const float*)d_in[8];
  const float* wv_win = (const float*)d_in[9];
  const float* block_pos = (const float*)d_in[10];
  const float* ck1_w = (const float*)d_in[11];
  const float* ck1_b = (const float*)d_in[12];
  const float* ck2_w = (const float*)d_in[13];
  const float* ck2_b = (const float*)d_in[14];
  const float* cv1_w = (const float*)d_in[15];
  const float* cv1_b = (const float*)d_in[16];
  const float* cv2_w = (const float*)d_in[17];
  const float* cv2_b = (const float*)d_in[18];
  float* out = (float*)d_out;

  char* wsp = (char*)d_ws;
  // [0, 10485760)         kvproj f32 2048x1280
  // [10485760, 18874368)  kvbf bf16 2048x2048 (K slices); earlier: k_cmp partials (2x4.19MB)
  // [18874368, 23068672)  VT bf16 (16 slices x 128 x 1024)
  // [23068672, 31457280)  xbf  -> later hk_part/hv_part -> out2 (w/ next region)
  // [31457280, 44040192)  xlo + Wk_hi + Wk_lo  -> later Wcat (11 MB)
  // [44040192, ...)       bias_cat | selB | hk | hv | k_sum | v_sum | bias_k/v
  float* kvproj = (float*)wsp;
  bf16_t* kvbf = (bf16_t*)(wsp + 10485760);
  float* part = (float*)(wsp + 10485760);     // k_cmp partials, dead before kvbf written
  bf16_t* VT = (bf16_t*)(wsp + 18874368);
  bf16_t* xbf = (bf16_t*)(wsp + 23068672);
  bf16_t* xlo = (bf16_t*)(wsp + 31457280);
  bf16_t* Wk_hi = (bf16_t*)(wsp + 39845888);
  bf16_t* Wk_lo = (bf16_t*)(wsp + 41943040);
  bf16_t* Wcat = (bf16_t*)(wsp + 31457280);   // overwrites xlo/Wk after gemm_prec
  float* bias_cat = (float*)(wsp + 44040192);
  unsigned long long* selB = (unsigned long long*)(wsp + 44052992);
  float* hk = (float*)(wsp + 44118528);
  float* hv = (float*)(wsp + 44376576);
  float* k_sum = (float*)(wsp + 44634624);
  float* v_sum = (float*)(wsp + 44892672);
  float* bias_k = (float*)(wsp + 45150720);
  float* bias_v = (float*)(wsp + 45151232);

  float* hk_part = (float*)(wsp + 23068672);  // xbf region (dead after GEMMs)
  float* hv_part = (float*)(wsp + 27197440);
  float* out2 = (float*)(wsp + 23068672);     // 16 MB (parts/Wcat dead by then)

  dim3 blk256(256);

  prep_kernel<<<20480, blk256, 0, stream>>>(x, xbf, xlo, wk_cmp, Wk_hi, Wk_lo);

  // k_cmp cols 0..511: hi/lo split bf16 MFMA, BN=64 split-K x2 (256 wgs) -> partials
  gemm_prec<<<dim3(8, 16, 2), blk256, 0, stream>>>(xbf, xlo, Wk_hi, Wk_lo, part);
  rope_k_fused2<<<Bc * Tc * NKVc, 64, 0, stream>>>(part, kvproj);

  // build Wcat now that xlo/Wk are dead (overwrites their region)
  build_wcat<<<21504, blk256, 0, stream>>>(wv_cmp, wk_slc, wv_slc, wk_win,
                                           wv_win, gate_w, gate_b, Wcat, bias_cat);
  gemm_mfma<<<dim3(42, 16), blk256, 0, stream>>>(
      xbf, 2048, Wcat, 2048, kvproj, kvbf, VT, bias_cat, 2048);

  rope_bf<<<dim3(Bc * Tc * NKVc, 2), 64, 0, stream>>>(kvbf);

  bias_adj_kernel<<<dim3(128, 2), blk256, 0, stream>>>(block_pos, ck1_w, ck1_b,
                                                       cv1_w, cv1_b, bias_k, bias_v);
  gemm_cmp1<<<dim3(2, 8, 32), blk256, 0, stream>>>(kvproj, ck1_w, cv1_w,
                                                   hk_part, hv_part);
  reduce_gelu<<<504, blk256, 0, stream>>>(hk_part, hv_part, bias_k, bias_v, hk, hv);
  gemm_l2<<<dim3(2, 8, 2), blk256, 0, stream>>>(hk, ck2_w, ck2_b, hv, cv2_w,
                                                cv2_b, k_sum, v_sum);

  cmp_attn<<<2048, blk256, 0, stream>>>(q, k_sum, v_sum, kvproj, out, selB);
  sparse_attn_mfma<<<1024, blk256, 0, stream>>>(q, kvbf, VT, kvproj, selB, out, out2);
  add_out<<<16384, blk256, 0, stream>>>(out, out2);
}

// Round 14
// 322.638 us; speedup vs baseline: 1.1057x; 1.1057x over previous
//
#include <hip/hip_runtime.h>
#include <hip/hip_bf16.h>
#include <math.h>

#define Bc 2
#define Tc 1024
#define DMc 2048
#define NQc 16
#define NKVc 4
#define DHc 128
#define BLKc 32
#define STRIDEc 16
#define TOPNc 16
#define WINc 512
#define NREPc 4
#define NBc 63
#define SCALEc 0.08838834764831843f
#define KVP_LD 1280   // kvproj f32: 0..511 k_cmp | 512..1023 v_cmp | 1024..1071 gates | pad
#define KVB_LD 2048   // kvbf bf16: 0..511 k_slc | 1024..1535 k_win (v slices go to VT)

typedef unsigned short bf16_t;
typedef short s16x8 __attribute__((ext_vector_type(8)));
typedef float f32x4 __attribute__((ext_vector_type(4)));
typedef unsigned short u16x4 __attribute__((ext_vector_type(4)));
typedef unsigned int u32x4 __attribute__((ext_vector_type(4)));

__device__ __forceinline__ unsigned short f2bf(float f) {
  unsigned int u = __float_as_uint(f);
  u += 0x7fffu + ((u >> 16) & 1u);
  return (unsigned short)(u >> 16);
}
__device__ __forceinline__ float bf2f(unsigned short h) {
  return __uint_as_float((unsigned int)h << 16);
}
__device__ __forceinline__ float geluf(float x) {
  return 0.5f * x * (1.0f + erff(x * 0.7071067811865476f));
}
__device__ __forceinline__ void load_lds16(const void* g, void* l) {
  __builtin_amdgcn_global_load_lds(
      (const __attribute__((address_space(1))) void*)g,
      (__attribute__((address_space(3))) void*)l, 16, 0, 0);
}

// ---------- prep (float4): x->hi/lo, wk_cmp->hi/lo ----------
__global__ void prep_kernel(const float* __restrict__ x, bf16_t* __restrict__ xbf,
                            bf16_t* __restrict__ xlo,
                            const float* __restrict__ wk_cmp,
                            bf16_t* __restrict__ Wk_hi, bf16_t* __restrict__ Wk_lo) {
  size_t gid = (size_t)blockIdx.x * 256 + threadIdx.x;  // exact: 1310720/256 = 5120
  const float* src;
  bf16_t *dh, *dl;
  size_t i;
  if (gid < 1048576) {
    i = gid * 4;
    src = x; dh = xbf; dl = xlo;
  } else {
    i = (gid - 1048576) * 4;
    src = wk_cmp; dh = Wk_hi; dl = Wk_lo;
  }
  f32x4 f = *(const f32x4*)(src + i);
  u16x4 h, l;
#pragma unroll
  for (int e = 0; e < 4; ++e) {
    h[e] = f2bf(f[e]);
    l[e] = f2bf(f[e] - bf2f(h[e]));
  }
  *(u16x4*)(dh + i) = h;
  *(u16x4*)(dl + i) = l;
}

// ---------- concat weights rows 512..3199 into bf16 Wcat ----------
__global__ void build_wcat(
    const float* __restrict__ wv_cmp, const float* __restrict__ wk_slc,
    const float* __restrict__ wv_slc, const float* __restrict__ wk_win,
    const float* __restrict__ wv_win, const float* __restrict__ gate_w,
    const float* __restrict__ gate_b, bf16_t* __restrict__ Wcat,
    float* __restrict__ bias_cat) {
  size_t i = (size_t)blockIdx.x * 256 + threadIdx.x;  // exact: 2688*2048/256
  int rr = (int)(i >> 11), c = (int)(i & 2047);
  int r = rr + 512;
  float v = 0.f;
  if (r < 3072) {
    int blk = r >> 9;  // 1..5
    size_t o = (size_t)(r & 511) * 2048 + c;
    if (blk == 1) v = wv_cmp[o];
    else if (blk == 2) v = wk_slc[o];
    else if (blk == 3) v = wv_slc[o];
    else if (blk == 4) v = wk_win[o];
    else v = wv_win[o];
  } else if (r < 3120) {
    v = gate_w[(size_t)(r - 3072) * 2048 + c];
  }
  Wcat[i] = f2bf(v);
  if (c == 0) bias_cat[r] = (r >= 3072 && r < 3120) ? gate_b[r - 3072] : 0.f;
}

// ---------- hi/lo split-bf16 MFMA GEMM for k_cmp, BM=128 BN=64, split-K x2 ----------
__global__ __launch_bounds__(256) void gemm_prec(
    const bf16_t* __restrict__ A, const bf16_t* __restrict__ Alo,
    const bf16_t* __restrict__ Bw, const bf16_t* __restrict__ Blo,
    float* __restrict__ part) {
  __shared__ bf16_t As[2 * 128 * 32];
  __shared__ bf16_t Bs[2 * 64 * 32];
  const int z = blockIdx.z;
  const int bm = blockIdx.y * 128, bnw = blockIdx.x * 64;
  const int tid = threadIdx.x, lane = tid & 63, w = tid >> 6;
  const int wr = (w >> 1) * 64, wc = (w & 1) * 32;
  const int kbase = z * 1024;

  f32x4 acc[4][2];
#pragma unroll
  for (int i = 0; i < 4; ++i)
#pragma unroll
    for (int j = 0; j < 2; ++j) acc[i][j] = 0.f;

  const int srow = lane >> 2;
  const int sslot = lane & 3;

  for (int k0 = kbase; k0 < kbase + 1024; k0 += 32) {
    __syncthreads();
#pragma unroll
    for (int j = 0; j < 2; ++j) {  // A hi/lo: 128 rows each
      int rb = w * 32 + j * 16;
      int row = rb + srow;
      int slot = sslot ^ ((row >> 1) & 3);
      load_lds16(A + (size_t)(bm + row) * 2048 + k0 + slot * 8, &As[rb * 32]);
      load_lds16(Alo + (size_t)(bm + row) * 2048 + k0 + slot * 8, &As[4096 + rb * 32]);
    }
    {  // B hi/lo: 64 rows each
      int rb = w * 16;
      int row = rb + srow;
      int slot = sslot ^ ((row >> 1) & 3);
      load_lds16(Bw + (size_t)(bnw + row) * 2048 + k0 + slot * 8, &Bs[rb * 32]);
      load_lds16(Blo + (size_t)(bnw + row) * 2048 + k0 + slot * 8, &Bs[2048 + rb * 32]);
    }
    __syncthreads();

    s16x8 af[4], afl[4], bfr[2], bfl[2];
#pragma unroll
    for (int i = 0; i < 4; ++i) {
      int ar = wr + i * 16 + (lane & 15);
      int as = ((lane >> 4) ^ ((ar >> 1) & 3)) * 8;
      af[i] = *(const s16x8*)&As[ar * 32 + as];
      afl[i] = *(const s16x8*)&As[4096 + ar * 32 + as];
    }
#pragma unroll
    for (int j = 0; j < 2; ++j) {
      int br = wc + j * 16 + (lane & 15);
      int bs = ((lane >> 4) ^ ((br >> 1) & 3)) * 8;
      bfr[j] = *(const s16x8*)&Bs[br * 32 + bs];
      bfl[j] = *(const s16x8*)&Bs[2048 + br * 32 + bs];
    }
#pragma unroll
    for (int i = 0; i < 4; ++i)
#pragma unroll
      for (int j = 0; j < 2; ++j) {
        acc[i][j] = __builtin_amdgcn_mfma_f32_16x16x32_bf16(afl[i], bfr[j], acc[i][j], 0, 0, 0);
        acc[i][j] = __builtin_amdgcn_mfma_f32_16x16x32_bf16(af[i], bfl[j], acc[i][j], 0, 0, 0);
        acc[i][j] = __builtin_amdgcn_mfma_f32_16x16x32_bf16(af[i], bfr[j], acc[i][j], 0, 0, 0);
      }
  }

  float* pz = part + (size_t)z * 1048576;
#pragma unroll
  for (int i = 0; i < 4; ++i) {
    int row = bm + wr + i * 16 + ((lane >> 4) << 2);
#pragma unroll
    for (int j = 0; j < 2; ++j) {
      int col = bnw + wc + j * 16 + (lane & 15);
#pragma unroll
      for (int r = 0; r < 4; ++r)
        pz[(size_t)(row + r) * 512 + col] = acc[i][j][r];
    }
  }
}

// ---------- reduce 2 k_cmp partials + RoPE -> kvproj cols 0..511 ----------
__global__ void rope_k_fused2(const float* __restrict__ part,
                              float* __restrict__ kvproj) {
  int blk = blockIdx.x;  // (b*T+t)*KV+kv
  int kv = blk & 3;
  int t = (blk >> 2) & (Tc - 1);
  int b = blk >> 12;
  int d = threadIdx.x;  // 0..63
  size_t base = (size_t)(b * Tc + t) * 512 + kv * 128;
  float x1 = part[base + d] + part[1048576 + base + d];
  float x2 = part[base + d + 64] + part[1048576 + base + d + 64];
  float inv = powf(10000.f, -(float)d * (1.f / 64.f));
  float ang = (float)t * inv;
  float s, c;
  sincosf(ang, &s, &c);
  float* p = kvproj + (size_t)(b * Tc + t) * KVP_LD + kv * 128;
  p[d] = x1 * c - x2 * s;
  p[d + 64] = x1 * s + x2 * c;
}

// ---------- bf16 MFMA GEMM: cols 512..3199, BM=128 BN=64 ----------
__global__ __launch_bounds__(256) void gemm_mfma(
    const bf16_t* __restrict__ A, int lda,
    const bf16_t* __restrict__ Bw, int ldb,
    float* __restrict__ kvproj, bf16_t* __restrict__ kvbf,
    bf16_t* __restrict__ VT, const float* __restrict__ bias, int K) {
  __shared__ bf16_t As[128 * 32];
  __shared__ bf16_t Bs[64 * 32];
  const int bm = blockIdx.y * 128, bnw = blockIdx.x * 64, bn = 512 + bnw;
  const int tid = threadIdx.x, lane = tid & 63, w = tid >> 6;
  const int wr = (w >> 1) * 64, wc = (w & 1) * 32;

  f32x4 acc[4][2];
#pragma unroll
  for (int i = 0; i < 4; ++i)
#pragma unroll
    for (int j = 0; j < 2; ++j) acc[i][j] = 0.f;

  const int srow = lane >> 2;
  const int sslot = lane & 3;

  for (int k0 = 0; k0 < K; k0 += 32) {
    __syncthreads();
#pragma unroll
    for (int j = 0; j < 2; ++j) {
      int rb = w * 32 + j * 16;
      int row = rb + srow;
      int slot = sslot ^ ((row >> 1) & 3);
      load_lds16(A + (size_t)(bm + row) * lda + k0 + slot * 8, &As[rb * 32]);
    }
    {
      int rb = w * 16;
      int row = rb + srow;
      int slot = sslot ^ ((row >> 1) & 3);
      load_lds16(Bw + (size_t)(bnw + row) * ldb + k0 + slot * 8, &Bs[rb * 32]);
    }
    __syncthreads();

    s16x8 af[4], bfr[2];
#pragma unroll
    for (int i = 0; i < 4; ++i) {
      int ar = wr + i * 16 + (lane & 15);
      int as = ((lane >> 4) ^ ((ar >> 1) & 3)) * 8;
      af[i] = *(const s16x8*)&As[ar * 32 + as];
    }
#pragma unroll
    for (int j = 0; j < 2; ++j) {
      int br = wc + j * 16 + (lane & 15);
      int bs = ((lane >> 4) ^ ((br >> 1) & 3)) * 8;
      bfr[j] = *(const s16x8*)&Bs[br * 32 + bs];
    }
#pragma unroll
    for (int i = 0; i < 4; ++i)
#pragma unroll
      for (int j = 0; j < 2; ++j)
        acc[i][j] = __builtin_amdgcn_mfma_f32_16x16x32_bf16(af[i], bfr[j], acc[i][j], 0, 0, 0);
  }

#pragma unroll
  for (int i = 0; i < 4; ++i) {
    int row = bm + wr + i * 16 + ((lane >> 4) << 2);
#pragma unroll
    for (int j = 0; j < 2; ++j) {
      int col = bn + wc + j * 16 + (lane & 15);
      float bv = bias[col];
      float vals[4];
#pragma unroll
      for (int r = 0; r < 4; ++r) vals[r] = acc[i][j][r] + bv;
      if (col < 1024) {  // v_cmp -> f32 kvproj
#pragma unroll
        for (int r = 0; r < 4; ++r)
          kvproj[(size_t)(row + r) * KVP_LD + col] = vals[r];
      } else if (col < 3072) {
        int cc = col - 1024;
        int region = cc >> 9;  // 0 k_slc, 1 v_slc, 2 k_win, 3 v_win
        if ((region & 1) == 0) {
#pragma unroll
          for (int r = 0; r < 4; ++r)
            kvbf[(size_t)(row + r) * KVB_LD + cc] = f2bf(vals[r]);
        } else {
          int mode = region >> 1;
          int kv = (cc >> 7) & 3, d = cc & 127;
          int b = row >> 10;
          u16x4 w4;
#pragma unroll
          for (int r = 0; r < 4; ++r) w4[r] = f2bf(vals[r]);
          *(u16x4*)(VT + (size_t)((b * 4 + kv) * 2 + mode) * 131072 +
                    d * 1024 + (row & 1023)) = w4;
        }
      } else {
#pragma unroll
        for (int r = 0; r < 4; ++r)
          kvproj[(size_t)(row + r) * KVP_LD + (col - 2048)] =
              1.f / (1.f + __expf(-vals[r]));
      }
    }
  }
}

// ---------- RoPE in place on kvbf K slices (bf16) ----------
__global__ void rope_bf(bf16_t* __restrict__ kvbf) {
  int blk = blockIdx.x;
  int coloff = blockIdx.y << 10;  // 0 (slc K) or 1024 (win K)
  int kv = blk & 3;
  int t = (blk >> 2) & (Tc - 1);
  int b = blk >> 12;
  bf16_t* p = kvbf + (size_t)(b * Tc + t) * KVB_LD + coloff + kv * 128;
  int d = threadIdx.x;
  float inv = powf(10000.f, -(float)d * (1.f / 64.f));
  float ang = (float)t * inv;
  float s, c;
  sincosf(ang, &s, &c);
  float x1 = bf2f(p[d]), x2 = bf2f(p[d + 64]);
  p[d] = f2bf(x1 * c - x2 * s);
  p[d + 64] = f2bf(x1 * s + x2 * c);
}

// ---------- compress layer1: gathered-A GEMM, split-K x16, k&v merged ----------
__global__ __launch_bounds__(256) void gemm_cmp1(
    const float* __restrict__ kvproj,
    const float* __restrict__ ck1_w, const float* __restrict__ cv1_w,
    float* __restrict__ hk_part, float* __restrict__ hv_part) {
  __shared__ float As[16][68];
  __shared__ float Ws[16][68];
  const int zz = blockIdx.z;
  const bool isv = zz >= 16;
  const int z = zz & 15;
  const int coloff = isv ? 512 : 0;
  const float* W = isv ? cv1_w : ck1_w;
  float* Cpart = isv ? hv_part : hk_part;
  const int bm = blockIdx.y * 64, bn = blockIdx.x * 64;
  const int tid = threadIdx.x;
  const int tx = tid & 15, ty = tid >> 4;
  float acc[4][4] = {{0.f}};
  for (int k0 = z * 256; k0 < z * 256 + 256; k0 += 16) {
#pragma unroll
    for (int i0 = 0; i0 < 4; ++i0) {
      int i = tid + i0 * 256;
      int m = i >> 4, kk = i & 15;
      int gm = bm + m;
      float av = 0.f;
      if (gm < 504) {
        int b = gm / 252, rem = gm % 252;
        int n = rem >> 2, kv = rem & 3;
        int f = k0 + kk;
        int j = f >> 7, d = f & 127;
        av = kvproj[(size_t)(b * Tc + n * 16 + j) * KVP_LD + coloff + kv * 128 + d];
      }
      As[kk][m] = av;
      Ws[kk][m] = W[(size_t)(bn + m) * 4096 + (k0 + kk)];
    }
    __syncthreads();
#pragma unroll
    for (int kk = 0; kk < 16; ++kk) {
      float4 a4 = *reinterpret_cast<const float4*>(&As[kk][ty * 4]);
      float4 w4 = *reinterpret_cast<const float4*>(&Ws[kk][tx * 4]);
      float av[4] = {a4.x, a4.y, a4.z, a4.w};
      float wv[4] = {w4.x, w4.y, w4.z, w4.w};
#pragma unroll
      for (int i = 0; i < 4; ++i)
#pragma unroll
        for (int j = 0; j < 4; ++j) acc[i][j] = fmaf(av[i], wv[j], acc[i][j]);
    }
    __syncthreads();
  }
#pragma unroll
  for (int i = 0; i < 4; ++i) {
    int m = bm + ty * 4 + i;
    if (m >= 504) continue;
#pragma unroll
    for (int j = 0; j < 4; ++j)
      Cpart[(size_t)z * 64512 + (size_t)m * 128 + bn + tx * 4 + j] = acc[i][j];
  }
}

// ---------- bias_adj[o] = b1[o] + block_pos_flat . w1[o,:] ----------
__global__ void bias_adj_kernel(const float* __restrict__ bp,
                                const float* __restrict__ w1k,
                                const float* __restrict__ b1k,
                                const float* __restrict__ w1v,
                                const float* __restrict__ b1v,
                                float* __restrict__ outk,
                                float* __restrict__ outv) {
  __shared__ float red[4];
  const int o = blockIdx.x;
  const float* w1 = blockIdx.y ? w1v : w1k;
  float s = 0.f;
  for (int i = threadIdx.x; i < 4096; i += 256)
    s += bp[i] * w1[(size_t)o * 4096 + i];
#pragma unroll
  for (int off = 32; off; off >>= 1) s += __shfl_xor(s, off);
  if ((threadIdx.x & 63) == 0) red[threadIdx.x >> 6] = s;
  __syncthreads();
  if (threadIdx.x == 0) {
    float t = red[0] + red[1] + red[2] + red[3];
    if (blockIdx.y) outv[o] = t + b1v[o];
    else outk[o] = t + b1k[o];
  }
}

// ---------- reduce 16 partials + bias + gelu, k&v merged ----------
__global__ void reduce_gelu(const float* __restrict__ hk_part,
                            const float* __restrict__ hv_part,
                            const float* __restrict__ bias_k,
                            const float* __restrict__ bias_v,
                            float* __restrict__ hk, float* __restrict__ hv) {
  int gi = blockIdx.x * 256 + threadIdx.x;  // exact: 2*64512/256
  const bool isv = gi >= 64512;
  int i = isv ? gi - 64512 : gi;
  const float* parts = isv ? hv_part : hk_part;
  float s = (isv ? bias_v : bias_k)[i & 127];
#pragma unroll
  for (int z = 0; z < 16; ++z) s += parts[z * 64512 + i];
  (isv ? hv : hk)[i] = geluf(s);
}

// ---------- compress layer2, k&v merged ----------
__global__ __launch_bounds__(256) void gemm_l2(
    const float* __restrict__ hk, const float* __restrict__ w2k,
    const float* __restrict__ b2k, const float* __restrict__ hv,
    const float* __restrict__ w2v, const float* __restrict__ b2v,
    float* __restrict__ k_sum, float* __restrict__ v_sum) {
  __shared__ float As[16][68];
  __shared__ float Ws[16][68];
  const bool isv = blockIdx.z != 0;
  const float* A = isv ? hv : hk;
  const float* W = isv ? w2v : w2k;
  const float* bias = isv ? b2v : b2k;
  float* C = isv ? v_sum : k_sum;
  const int bm = blockIdx.y * 64, bn = blockIdx.x * 64;
  const int tid = threadIdx.x;
  const int tx = tid & 15, ty = tid >> 4;
  float acc[4][4] = {{0.f}};
  for (int k0 = 0; k0 < 128; k0 += 16) {
#pragma unroll
    for (int i0 = 0; i0 < 4; ++i0) {
      int i = tid + i0 * 256;
      int m = i >> 4, kk = i & 15;
      int gm = bm + m;
      As[kk][m] = (gm < 504) ? A[(size_t)gm * 128 + (k0 + kk)] : 0.f;
      Ws[kk][m] = W[(size_t)(bn + m) * 128 + (k0 + kk)];
    }
    __syncthreads();
#pragma unroll
    for (int kk = 0; kk < 16; ++kk) {
      float4 a4 = *reinterpret_cast<const float4*>(&As[kk][ty * 4]);
      float4 w4 = *reinterpret_cast<const float4*>(&Ws[kk][tx * 4]);
      float av[4] = {a4.x, a4.y, a4.z, a4.w};
      float wv[4] = {w4.x, w4.y, w4.z, w4.w};
#pragma unroll
      for (int i = 0; i < 4; ++i)
#pragma unroll
        for (int j = 0; j < 4; ++j) acc[i][j] = fmaf(av[i], wv[j], acc[i][j]);
    }
    __syncthreads();
  }
#pragma unroll
  for (int i = 0; i < 4; ++i) {
    int m = bm + ty * 4 + i;
    if (m >= 504) continue;
#pragma unroll
    for (int j = 0; j < 4; ++j)
      C[(size_t)m * 128 + bn + tx * 4 + j] = acc[i][j] + bias[bn + tx * 4 + j];
  }
}

// ---------- compressed attention + top-k: 4 query tokens per wg ----------
__global__ __launch_bounds__(256) void cmp_attn(
    const float* __restrict__ q, const float* __restrict__ k_sum,
    const float* __restrict__ v_sum, const float* __restrict__ kvproj,
    float* __restrict__ out, unsigned long long* __restrict__ sel) {
  __shared__ __align__(16) float q_s[4][4][128];
  __shared__ __align__(16) float ks[NBc * 128];
  __shared__ float p_s[4][4][64];

  const int wg = blockIdx.x;  // (b*4+kv)*256 + tq
  const int tq = wg & 255;
  const int kv = (wg >> 8) & 3;
  const int b = wg >> 10;
  const int t0 = tq * 4;
  const int tid = threadIdx.x;
  const int lane = tid & 63;
  const int g = tid >> 6;

  for (int i = tid; i < 2048; i += 256) {
    int gg = i >> 9, r = (i >> 7) & 3, d = i & 127;
    q_s[gg][r][d] = q[(((size_t)b * NQc + gg * NKVc + kv) * Tc + t0 + r) * 128 + d];
  }
  {
    const float* kbase = k_sum + (size_t)(b * 252 + kv) * 128;
    for (int i = tid; i < NBc * 32; i += 256) {
      int n = i >> 5, s = i & 31;
      f32x4 v4 = *(const f32x4*)(kbase + (size_t)n * 512 + s * 4);
      *(f32x4*)&ks[n * 128 + ((s ^ (n & 7)) << 2)] = v4;
    }
  }
  __syncthreads();

  float acc[4] = {0.f, 0.f, 0.f, 0.f};
  {
    const int lrow = (lane < 63) ? lane : 62;
    const int lx = lrow & 7;
#pragma unroll
    for (int s = 0; s < 32; ++s) {
      f32x4 k4 = *(const f32x4*)&ks[lrow * 128 + ((s ^ lx) << 2)];
#pragma unroll
      for (int r = 0; r < 4; ++r) {
        f32x4 q4 = *(const f32x4*)&q_s[g][r][s * 4];
        acc[r] = fmaf(q4[0], k4[0], acc[r]);
        acc[r] = fmaf(q4[1], k4[1], acc[r]);
        acc[r] = fmaf(q4[2], k4[2], acc[r]);
        acc[r] = fmaf(q4[3], k4[3], acc[r]);
      }
    }
  }
#pragma unroll
  for (int r = 0; r < 4; ++r) {
    const int t = t0 + r;
    const int nvalid = min(t / STRIDEc + 1, NBc);
    const bool valid = (lane < nvalid);
    float sval = valid ? acc[r] * SCALEc : -INFINITY;
    float m = sval;
#pragma unroll
    for (int off = 32; off; off >>= 1) m = fmaxf(m, __shfl_xor(m, off));
    float e = valid ? __expf(sval - m) : 0.f;
    float l = e;
#pragma unroll
    for (int off = 32; off; off >>= 1) l += __shfl_xor(l, off);
    p_s[g][r][lane] = e / fmaxf(l, 1e-9f);
  }
  __syncthreads();

  {  // top-k: wave g handles row r=g
    float v = p_s[0][g][lane] + p_s[1][g][lane] + p_s[2][g][lane] + p_s[3][g][lane];
    if (lane >= NBc) v = -1.f;
    unsigned long long mask = 0ull;
    for (int it = 0; it < TOPNc; ++it) {
      float mx = v;
#pragma unroll
      for (int off = 32; off; off >>= 1) mx = fmaxf(mx, __shfl_xor(mx, off));
      unsigned long long ball = __ballot(v == mx);
      int sl = __ffsll(ball) - 1;
      mask |= 1ull << sl;
      if (lane == sl) v = -1.f;
    }
    if (lane == 0) sel[(((size_t)b * NKVc + kv) << 10) + t0 + g] = mask;
  }
  {
    const float* vbase = v_sum + (size_t)(b * 252 + kv) * 128;
    for (int i = tid; i < NBc * 32; i += 256) {
      int n = i >> 5, s = i & 31;
      f32x4 v4 = *(const f32x4*)(vbase + (size_t)n * 512 + s * 4);
      *(f32x4*)&ks[n * 128 + ((s ^ (n & 7)) << 2)] = v4;
    }
  }
  __syncthreads();

  const int h = g * NKVc + kv;
  float ox[4] = {0.f, 0.f, 0.f, 0.f}, oy[4] = {0.f, 0.f, 0.f, 0.f};
  const int slotd = lane >> 1, wi = (lane & 1) * 2;
  const int nvmax = min((t0 + 3) / STRIDEc + 1, NBc);
  for (int n = 0; n < nvmax; ++n) {
    const float* vp = &ks[n * 128 + (((slotd ^ (n & 7)) << 2) | wi)];
    const float vx = vp[0], vy = vp[1];
#pragma unroll
    for (int r = 0; r < 4; ++r) {
      float pn = p_s[g][r][n];
      ox[r] = fmaf(pn, vx, ox[r]);
      oy[r] = fmaf(pn, vy, oy[r]);
    }
  }
#pragma unroll
  for (int r = 0; r < 4; ++r) {
    const int t = t0 + r;
    const float g0 = kvproj[(size_t)(b * Tc + t) * KVP_LD + 1024 + h * 3];
    size_t obase = ((size_t)(b * NQc + h) * Tc + t) * 128 + lane * 2;
    *(float2*)&out[obase] = make_float2(g0 * ox[r], g0 * oy[r]);
  }
}

// ---------- merged MFMA flash-tile attention (swapped-QK, in-register P) ----------
// R12-proven config: QBLK=32, 8 waves, chunk=64, dbuf, grid 512.
// Co-resident pair (wgi, wgi^256) differs in MODE with anti-correlated tiles.
__global__ __launch_bounds__(512, 4) void sparse_attn_mfma(
    const float* __restrict__ q, const bf16_t* __restrict__ kvbf,
    const bf16_t* __restrict__ VT, const float* __restrict__ kvproj,
    const unsigned long long* __restrict__ sel,
    float* __restrict__ out, float* __restrict__ out2) {
  __shared__ bf16_t KsB[2][64 * 128];   // [s][d], swz ^((s&7)<<4) via pre-swz source
  __shared__ bf16_t VtB[2][128 * 64];   // [d][s], swz ^(((d>>1)&7)<<4)

  const int wgi = blockIdx.x;
  const int b = wgi & 1;
  const int kv = (wgi >> 1) & 3;
  const int Y = (wgi >> 3) & 31;
  const int mode = (wgi >> 8) & 1;
  const int tt = mode ? Y : 31 - Y;
  const int t0 = tt * 32;
  const int tid = threadIdx.x, lane = tid & 63;
  const int wv = tid >> 6;   // 0..7
  const int g = wv & 3;      // head
  const int half = wv >> 2;  // row-half
  const int t0h = t0 + half * 16;
  const int h = g * NKVc + kv;
  const int lr = lane >> 4;
  const int lc = lane & 15;
  const int tL = t0h + lc;   // this lane's softmax column (query row)

  s16x8 aq[4];
  {
    const float* qrow = q + (((size_t)(b * NQc + h) * Tc) + tL) * 128;
#pragma unroll
    for (int ks = 0; ks < 4; ++ks) {
      f32x4 lo = *(const f32x4*)(qrow + ks * 32 + lr * 8);
      f32x4 hi = *(const f32x4*)(qrow + ks * 32 + lr * 8 + 4);
      s16x8 v;
#pragma unroll
      for (int e = 0; e < 4; ++e) {
        v[e] = (short)f2bf(lo[e]);
        v[e + 4] = (short)f2bf(hi[e]);
      }
      aq[ks] = v;
    }
  }

  unsigned long long hm = ~0ull;
  unsigned long long um = ~0ull;
  int c0;
  const int c1 = (t0 + 31) >> 6;
  const unsigned long long* sb = sel + ((size_t)(b * NKVc + kv) << 10);
  if (mode == 0) {
    unsigned long long bm = sb[tL];
    hm = bm | (bm << 1);
    unsigned long long uu = 0ull;
    if (lane < 32) {
      unsigned long long b2 = sb[t0 + lane];
      uu = b2 | (b2 << 1);
    }
#pragma unroll
    for (int off = 32; off; off >>= 1) uu |= __shfl_xor(uu, off);
    um = uu;
    c0 = (__ffsll(um) - 1) >> 2;
  } else {
    int lo = t0 - (WINc - 1);
    c0 = (lo > 0 ? lo : 0) >> 6;
  }

  float run_m = -INFINITY, run_l = 0.f;
  f32x4 acc_o[8];
#pragma unroll
  for (int j = 0; j < 8; ++j) acc_o[j] = 0.f;

  const bf16_t* kb = kvbf + (mode << 10) + kv * 128;
  const bf16_t* vt = VT + (size_t)((b * 4 + kv) * 2 + mode) * 131072;
  const size_t rbase = (size_t)b * Tc;

  auto STAGE = [&](int bufi, int c) {
    const int s0 = c * 64;
#pragma unroll
    for (int p = 0; p < 2; ++p) {
      int o = p * 512 + tid;
      int s = o >> 4, sl = o & 15;
      int slot = sl ^ (s & 7);
      load_lds16(kb + (rbase + s0 + s) * KVB_LD + slot * 8,
                 (char*)&KsB[bufi][0] + (p * 512 + wv * 64) * 16);
    }
#pragma unroll
    for (int p = 0; p < 2; ++p) {
      int o = p * 512 + tid;
      int d = o >> 3, sl = o & 7;
      int slot = sl ^ ((d >> 1) & 7);
      load_lds16(vt + (size_t)d * 1024 + s0 + slot * 8,
                 (char*)&VtB[bufi][0] + (p * 512 + wv * 64) * 16);
    }
  };

  int c = c0;
  STAGE(0, c);
  int buf = 0;
  while (true) {
    int cn = c + 1;
    if (mode == 0)
      while (cn <= c1 && ((um >> (4 * cn)) & 0xFull) == 0ull) ++cn;
    __syncthreads();
    if (cn <= c1) STAGE(buf ^ 1, cn);

    const int s0 = c * 64;
    const char* KsP = (const char*)&KsB[buf][0];
    const char* VtP = (const char*)&VtB[buf][0];

    f32x4 accs[4];
#pragma unroll
    for (int j = 0; j < 4; ++j) accs[j] = 0.f;
    __builtin_amdgcn_s_setprio(1);
#pragma unroll
    for (int ks = 0; ks < 4; ++ks) {
      s16x8 bk[4];
#pragma unroll
      for (int j = 0; j < 4; ++j) {
        int sB = j * 16 + lc;
        bk[j] = *(const s16x8*)(KsP +
                                ((sB * 256 + (ks * 4 + lr) * 16) ^ ((sB & 7) << 4)));
      }
#pragma unroll
      for (int j = 0; j < 4; ++j)
        accs[j] = __builtin_amdgcn_mfma_f32_16x16x32_bf16(bk[j], aq[ks], accs[j], 0, 0, 0);
    }
    __builtin_amdgcn_s_setprio(0);

    float ev[4][4];
    float mx = -INFINITY;
#pragma unroll
    for (int j = 0; j < 4; ++j)
#pragma unroll
      for (int r = 0; r < 4; ++r) {
        int s = s0 + j * 16 + lr * 4 + r;
        bool att;
        if (mode == 0) att = (s <= tL) && ((hm >> (s >> 4)) & 1ull);
        else att = (s <= tL) && (tL - s < WINc);
        float sv = att ? accs[j][r] * SCALEc : -INFINITY;
        ev[j][r] = sv;
        mx = fmaxf(mx, sv);
      }
    mx = fmaxf(mx, __shfl_xor(mx, 16));
    mx = fmaxf(mx, __shfl_xor(mx, 32));
    const bool defer = __all(mx <= run_m + 8.f);
    float nm = run_m;
    if (!defer) {
      nm = fmaxf(run_m, mx);
      const float resc = (run_m == -INFINITY) ? 0.f : __expf(run_m - nm);
      float rs[4];
#pragma unroll
      for (int r = 0; r < 4; ++r) rs[r] = __shfl(resc, lr * 16 + lr * 4 + r);
#pragma unroll
      for (int jo = 0; jo < 8; ++jo)
#pragma unroll
        for (int r = 0; r < 4; ++r) acc_o[jo][r] *= rs[r];
      run_l *= resc;
      run_m = nm;
    }
    float cl = 0.f;
#pragma unroll
    for (int j = 0; j < 4; ++j)
#pragma unroll
      for (int r = 0; r < 4; ++r) {
        float e = (ev[j][r] == -INFINITY) ? 0.f : __expf(ev[j][r] - nm);
        ev[j][r] = e;
        cl += e;
      }
    cl += __shfl_xor(cl, 16);
    cl += __shfl_xor(cl, 32);
    run_l += cl;

    unsigned int pw[4][2];
#pragma unroll
    for (int j = 0; j < 4; ++j) {
      pw[j][0] = ((unsigned int)f2bf(ev[j][1]) << 16) | f2bf(ev[j][0]);
      pw[j][1] = ((unsigned int)f2bf(ev[j][3]) << 16) | f2bf(ev[j][2]);
    }

    s16x8 ap[2];
#pragma unroll
    for (int k2 = 0; k2 < 2; ++k2) {
      u32x4 words;
#pragma unroll
      for (int w = 0; w < 4; ++w) {
        int src = ((lr & 1) * 2 + (w >> 1)) * 16 + lc;
        unsigned int a0 = __shfl((int)pw[2 * k2][w & 1], src);
        unsigned int a1 = __shfl((int)pw[2 * k2 + 1][w & 1], src);
        words[w] = (lr >> 1) ? a1 : a0;
      }
      ap[k2] = __builtin_bit_cast(s16x8, words);
    }

    __builtin_amdgcn_s_setprio(1);
#pragma unroll
    for (int k2 = 0; k2 < 2; ++k2) {
#pragma unroll
      for (int jo = 0; jo < 8; ++jo) {
        int d = jo * 16 + lc;
        s16x8 bv = *(const s16x8*)(VtP +
                                   ((d * 128 + k2 * 64 + lr * 16) ^ (((d >> 1) & 7) << 4)));
        acc_o[jo] = __builtin_amdgcn_mfma_f32_16x16x32_bf16(ap[k2], bv, acc_o[jo], 0, 0, 0);
      }
    }
    __builtin_amdgcn_s_setprio(0);

    if (cn > c1) break;
    buf ^= 1;
    c = cn;
  }

  float rl[4];
#pragma unroll
  for (int r = 0; r < 4; ++r) rl[r] = __shfl(run_l, lr * 16 + lr * 4 + r);
#pragma unroll
  for (int r = 0; r < 4; ++r) {
    const int t = t0h + lr * 4 + r;
    const float gg = kvproj[(rbase + t) * KVP_LD + 1024 + h * 3 + 1 + mode];
    const float sc = gg / fmaxf(rl[r], 1e-9f);
    const size_t ob = ((size_t)(b * NQc + h) * Tc + t) * 128;
#pragma unroll
    for (int jo = 0; jo < 8; ++jo) {
      size_t oi = ob + jo * 16 + lc;
      float v = acc_o[jo][r] * sc;
      if (mode == 0) out[oi] += v;
      else out2[oi] = v;
    }
  }
}

// ---------- out += out2 (float4) ----------
__global__ void add_out(float* __restrict__ out, const float* __restrict__ out2) {
  size_t i = (size_t)blockIdx.x * 256 + threadIdx.x;  // exact: 1048576/256 = 4096
  f32x4 a = ((const f32x4*)out)[i];
  f32x4 bv = ((const f32x4*)out2)[i];
  ((f32x4*)out)[i] = a + bv;
}

extern "C" void kernel_launch(void* const* d_in, const int* in_sizes, int n_in,
                              void* d_out, int out_size, void* d_ws, size_t ws_size,
                              hipStream_t stream) {
  const float* x = (const float*)d_in[0];
  const float* q = (const float*)d_in[1];
  const float* gate_w = (const float*)d_in[2];
  const float* gate_b = (const float*)d_in[3];
  const float* wk_cmp = (const float*)d_in[4];
  const float* wv_cmp = (const float*)d_in[5];
  const float* wk_slc = (const float*)d_in[6];
  const float* wv_slc = (const float*)d_in[7];
  const float* wk_win = (const float*)d_in[8];
  const float* wv_win = (const float*)d_in[9];
  const float* block_pos = (const float*)d_in[10];
  const float* ck1_w = (const float*)d_in[11];
  const float* ck1_b = (const float*)d_in[12];
  const float* ck2_w = (const float*)d_in[13];
  const float* ck2_b = (const float*)d_in[14];
  const float* cv1_w = (const float*)d_in[15];
  const float* cv1_b = (const float*)d_in[16];
  const float* cv2_w = (const float*)d_in[17];
  const float* cv2_b = (const float*)d_in[18];
  float* out = (float*)d_out;

  char* wsp = (char*)d_ws;
  // [0, 10485760)         kvproj f32 2048x1280
  // [10485760, 18874368)  kvbf bf16 2048x2048 (K slices); earlier: k_cmp partials (2x4.19MB)
  // [18874368, 23068672)  VT bf16 (16 slices x 128 x 1024)
  // [23068672, 31457280)  xbf  -> later hk_part/hv_part -> out2 (w/ next region)
  // [31457280, 44040192)  xlo + Wk_hi + Wk_lo  -> later Wcat (11 MB)
  // [44040192, ...)       bias_cat | selB | hk | hv | k_sum | v_sum | bias_k/v
  float* kvproj = (float*)wsp;
  bf16_t* kvbf = (bf16_t*)(wsp + 10485760);
  float* part = (float*)(wsp + 10485760);     // k_cmp partials, dead before kvbf written
  bf16_t* VT = (bf16_t*)(wsp + 18874368);
  bf16_t* xbf = (bf16_t*)(wsp + 23068672);
  bf16_t* xlo = (bf16_t*)(wsp + 31457280);
  bf16_t* Wk_hi = (bf16_t*)(wsp + 39845888);
  bf16_t* Wk_lo = (bf16_t*)(wsp + 41943040);
  bf16_t* Wcat = (bf16_t*)(wsp + 31457280);   // overwrites xlo/Wk after gemm_prec
  float* bias_cat = (float*)(wsp + 44040192);
  unsigned long long* selB = (unsigned long long*)(wsp + 44052992);
  float* hk = (float*)(wsp + 44118528);
  float* hv = (float*)(wsp + 44376576);
  float* k_sum = (float*)(wsp + 44634624);
  float* v_sum = (float*)(wsp + 44892672);
  float* bias_k = (float*)(wsp + 45150720);
  float* bias_v = (float*)(wsp + 45151232);

  float* hk_part = (float*)(wsp + 23068672);  // xbf region (dead after GEMMs)
  float* hv_part = (float*)(wsp + 27197440);
  float* out2 = (float*)(wsp + 23068672);     // 16 MB (parts/Wcat dead by then)

  dim3 blk256(256);

  prep_kernel<<<5120, blk256, 0, stream>>>(x, xbf, xlo, wk_cmp, Wk_hi, Wk_lo);

  // k_cmp cols 0..511: hi/lo split bf16 MFMA, BN=64 split-K x2 (256 wgs) -> partials
  gemm_prec<<<dim3(8, 16, 2), blk256, 0, stream>>>(xbf, xlo, Wk_hi, Wk_lo, part);
  rope_k_fused2<<<Bc * Tc * NKVc, 64, 0, stream>>>(part, kvproj);

  // build Wcat now that xlo/Wk are dead (overwrites their region)
  build_wcat<<<21504, blk256, 0, stream>>>(wv_cmp, wk_slc, wv_slc, wk_win,
                                           wv_win, gate_w, gate_b, Wcat, bias_cat);
  gemm_mfma<<<dim3(42, 16), blk256, 0, stream>>>(
      xbf, 2048, Wcat, 2048, kvproj, kvbf, VT, bias_cat, 2048);

  rope_bf<<<dim3(Bc * Tc * NKVc, 2), 64, 0, stream>>>(kvbf);

  bias_adj_kernel<<<dim3(128, 2), blk256, 0, stream>>>(block_pos, ck1_w, ck1_b,
                                                       cv1_w, cv1_b, bias_k, bias_v);
  gemm_cmp1<<<dim3(2, 8, 32), blk256, 0, stream>>>(kvproj, ck1_w, cv1_w,
                                                   hk_part, hv_part);
  reduce_gelu<<<504, blk256, 0, stream>>>(hk_part, hv_part, bias_k, bias_v, hk, hv);
  gemm_l2<<<dim3(2, 8, 2), blk256, 0, stream>>>(hk, ck2_w, ck2_b, hv, cv2_w,
                                                cv2_b, k_sum, v_sum);

  cmp_attn<<<2048, blk256, 0, stream>>>(q, k_sum, v_sum, kvproj, out, selB);
  sparse_attn_mfma<<<512, dim3(512), 0, stream>>>(q, kvbf, VT, kvproj, selB, out, out2);
  add_out<<<4096, blk256, 0, stream>>>(out, out2);
}

// Round 15
// 318.389 us; speedup vs baseline: 1.1205x; 1.0133x over previous
//
#include <hip/hip_runtime.h>
#include <hip/hip_bf16.h>
#include <math.h>

#define Bc 2
#define Tc 1024
#define DMc 2048
#define NQc 16
#define NKVc 4
#define DHc 128
#define BLKc 32
#define STRIDEc 16
#define TOPNc 16
#define WINc 512
#define NREPc 4
#define NBc 63
#define SCALEc 0.08838834764831843f
#define KVP_LD 1280   // kvproj f32: 0..511 k_cmp | 512..1023 v_cmp | 1024..1071 gates | pad
#define KVB_LD 2048   // kvbf bf16: 0..511 k_slc | 1024..1535 k_win (v slices go to VT)

typedef unsigned short bf16_t;
typedef short s16x8 __attribute__((ext_vector_type(8)));
typedef float f32x4 __attribute__((ext_vector_type(4)));
typedef unsigned short u16x4 __attribute__((ext_vector_type(4)));
typedef unsigned int u32x4 __attribute__((ext_vector_type(4)));

__device__ __forceinline__ unsigned short f2bf(float f) {
  unsigned int u = __float_as_uint(f);
  u += 0x7fffu + ((u >> 16) & 1u);
  return (unsigned short)(u >> 16);
}
__device__ __forceinline__ float bf2f(unsigned short h) {
  return __uint_as_float((unsigned int)h << 16);
}
__device__ __forceinline__ float geluf(float x) {
  return 0.5f * x * (1.0f + erff(x * 0.7071067811865476f));
}
__device__ __forceinline__ void load_lds16(const void* g, void* l) {
  __builtin_amdgcn_global_load_lds(
      (const __attribute__((address_space(1))) void*)g,
      (__attribute__((address_space(3))) void*)l, 16, 0, 0);
}

// ---------- prep (float4): x->hi/lo, wk_cmp->hi/lo ----------
__global__ void prep_kernel(const float* __restrict__ x, bf16_t* __restrict__ xbf,
                            bf16_t* __restrict__ xlo,
                            const float* __restrict__ wk_cmp,
                            bf16_t* __restrict__ Wk_hi, bf16_t* __restrict__ Wk_lo) {
  size_t gid = (size_t)blockIdx.x * 256 + threadIdx.x;  // exact: 1310720/256 = 5120
  const float* src;
  bf16_t *dh, *dl;
  size_t i;
  if (gid < 1048576) {
    i = gid * 4;
    src = x; dh = xbf; dl = xlo;
  } else {
    i = (gid - 1048576) * 4;
    src = wk_cmp; dh = Wk_hi; dl = Wk_lo;
  }
  f32x4 f = *(const f32x4*)(src + i);
  u16x4 h, l;
#pragma unroll
  for (int e = 0; e < 4; ++e) {
    h[e] = f2bf(f[e]);
    l[e] = f2bf(f[e] - bf2f(h[e]));
  }
  *(u16x4*)(dh + i) = h;
  *(u16x4*)(dl + i) = l;
}

// ---------- concat weights rows 512..3199 into bf16 Wcat ----------
__global__ void build_wcat(
    const float* __restrict__ wv_cmp, const float* __restrict__ wk_slc,
    const float* __restrict__ wv_slc, const float* __restrict__ wk_win,
    const float* __restrict__ wv_win, const float* __restrict__ gate_w,
    const float* __restrict__ gate_b, bf16_t* __restrict__ Wcat,
    float* __restrict__ bias_cat) {
  size_t i = (size_t)blockIdx.x * 256 + threadIdx.x;  // exact: 2688*2048/256
  int rr = (int)(i >> 11), c = (int)(i & 2047);
  int r = rr + 512;
  float v = 0.f;
  if (r < 3072) {
    int blk = r >> 9;  // 1..5
    size_t o = (size_t)(r & 511) * 2048 + c;
    if (blk == 1) v = wv_cmp[o];
    else if (blk == 2) v = wk_slc[o];
    else if (blk == 3) v = wv_slc[o];
    else if (blk == 4) v = wk_win[o];
    else v = wv_win[o];
  } else if (r < 3120) {
    v = gate_w[(size_t)(r - 3072) * 2048 + c];
  }
  Wcat[i] = f2bf(v);
  if (c == 0) bias_cat[r] = (r >= 3072 && r < 3120) ? gate_b[r - 3072] : 0.f;
}

// ---------- hi/lo split-bf16 MFMA GEMM for k_cmp, BM=128 BN=64, split-K x2 ----------
__global__ __launch_bounds__(256) void gemm_prec(
    const bf16_t* __restrict__ A, const bf16_t* __restrict__ Alo,
    const bf16_t* __restrict__ Bw, const bf16_t* __restrict__ Blo,
    float* __restrict__ part) {
  __shared__ bf16_t As[2 * 128 * 32];
  __shared__ bf16_t Bs[2 * 64 * 32];
  const int z = blockIdx.z;
  const int bm = blockIdx.y * 128, bnw = blockIdx.x * 64;
  const int tid = threadIdx.x, lane = tid & 63, w = tid >> 6;
  const int wr = (w >> 1) * 64, wc = (w & 1) * 32;
  const int kbase = z * 1024;

  f32x4 acc[4][2];
#pragma unroll
  for (int i = 0; i < 4; ++i)
#pragma unroll
    for (int j = 0; j < 2; ++j) acc[i][j] = 0.f;

  const int srow = lane >> 2;
  const int sslot = lane & 3;

  for (int k0 = kbase; k0 < kbase + 1024; k0 += 32) {
    __syncthreads();
#pragma unroll
    for (int j = 0; j < 2; ++j) {  // A hi/lo: 128 rows each
      int rb = w * 32 + j * 16;
      int row = rb + srow;
      int slot = sslot ^ ((row >> 1) & 3);
      load_lds16(A + (size_t)(bm + row) * 2048 + k0 + slot * 8, &As[rb * 32]);
      load_lds16(Alo + (size_t)(bm + row) * 2048 + k0 + slot * 8, &As[4096 + rb * 32]);
    }
    {  // B hi/lo: 64 rows each
      int rb = w * 16;
      int row = rb + srow;
      int slot = sslot ^ ((row >> 1) & 3);
      load_lds16(Bw + (size_t)(bnw + row) * 2048 + k0 + slot * 8, &Bs[rb * 32]);
      load_lds16(Blo + (size_t)(bnw + row) * 2048 + k0 + slot * 8, &Bs[2048 + rb * 32]);
    }
    __syncthreads();

    s16x8 af[4], afl[4], bfr[2], bfl[2];
#pragma unroll
    for (int i = 0; i < 4; ++i) {
      int ar = wr + i * 16 + (lane & 15);
      int as = ((lane >> 4) ^ ((ar >> 1) & 3)) * 8;
      af[i] = *(const s16x8*)&As[ar * 32 + as];
      afl[i] = *(const s16x8*)&As[4096 + ar * 32 + as];
    }
#pragma unroll
    for (int j = 0; j < 2; ++j) {
      int br = wc + j * 16 + (lane & 15);
      int bs = ((lane >> 4) ^ ((br >> 1) & 3)) * 8;
      bfr[j] = *(const s16x8*)&Bs[br * 32 + bs];
      bfl[j] = *(const s16x8*)&Bs[2048 + br * 32 + bs];
    }
#pragma unroll
    for (int i = 0; i < 4; ++i)
#pragma unroll
      for (int j = 0; j < 2; ++j) {
        acc[i][j] = __builtin_amdgcn_mfma_f32_16x16x32_bf16(afl[i], bfr[j], acc[i][j], 0, 0, 0);
        acc[i][j] = __builtin_amdgcn_mfma_f32_16x16x32_bf16(af[i], bfl[j], acc[i][j], 0, 0, 0);
        acc[i][j] = __builtin_amdgcn_mfma_f32_16x16x32_bf16(af[i], bfr[j], acc[i][j], 0, 0, 0);
      }
  }

  float* pz = part + (size_t)z * 1048576;
#pragma unroll
  for (int i = 0; i < 4; ++i) {
    int row = bm + wr + i * 16 + ((lane >> 4) << 2);
#pragma unroll
    for (int j = 0; j < 2; ++j) {
      int col = bnw + wc + j * 16 + (lane & 15);
#pragma unroll
      for (int r = 0; r < 4; ++r)
        pz[(size_t)(row + r) * 512 + col] = acc[i][j][r];
    }
  }
}

// ---------- reduce 2 k_cmp partials + RoPE -> kvproj cols 0..511 ----------
// (powf kept: selection path stays bit-identical to passing baseline)
__global__ void rope_k_fused2(const float* __restrict__ part,
                              float* __restrict__ kvproj) {
  int blk = blockIdx.x;  // (b*T+t)*KV+kv
  int kv = blk & 3;
  int t = (blk >> 2) & (Tc - 1);
  int b = blk >> 12;
  int d = threadIdx.x;  // 0..63
  size_t base = (size_t)(b * Tc + t) * 512 + kv * 128;
  float x1 = part[base + d] + part[1048576 + base + d];
  float x2 = part[base + d + 64] + part[1048576 + base + d + 64];
  float inv = powf(10000.f, -(float)d * (1.f / 64.f));
  float ang = (float)t * inv;
  float s, c;
  sincosf(ang, &s, &c);
  float* p = kvproj + (size_t)(b * Tc + t) * KVP_LD + kv * 128;
  p[d] = x1 * c - x2 * s;
  p[d + 64] = x1 * s + x2 * c;
}

// ---------- bf16 MFMA GEMM: cols 512..3199, BM=128 BN=64 ----------
__global__ __launch_bounds__(256) void gemm_mfma(
    const bf16_t* __restrict__ A, int lda,
    const bf16_t* __restrict__ Bw, int ldb,
    float* __restrict__ kvproj, bf16_t* __restrict__ kvbf,
    bf16_t* __restrict__ VT, const float* __restrict__ bias, int K) {
  __shared__ bf16_t As[128 * 32];
  __shared__ bf16_t Bs[64 * 32];
  const int bm = blockIdx.y * 128, bnw = blockIdx.x * 64, bn = 512 + bnw;
  const int tid = threadIdx.x, lane = tid & 63, w = tid >> 6;
  const int wr = (w >> 1) * 64, wc = (w & 1) * 32;

  f32x4 acc[4][2];
#pragma unroll
  for (int i = 0; i < 4; ++i)
#pragma unroll
    for (int j = 0; j < 2; ++j) acc[i][j] = 0.f;

  const int srow = lane >> 2;
  const int sslot = lane & 3;

  for (int k0 = 0; k0 < K; k0 += 32) {
    __syncthreads();
#pragma unroll
    for (int j = 0; j < 2; ++j) {
      int rb = w * 32 + j * 16;
      int row = rb + srow;
      int slot = sslot ^ ((row >> 1) & 3);
      load_lds16(A + (size_t)(bm + row) * lda + k0 + slot * 8, &As[rb * 32]);
    }
    {
      int rb = w * 16;
      int row = rb + srow;
      int slot = sslot ^ ((row >> 1) & 3);
      load_lds16(Bw + (size_t)(bnw + row) * ldb + k0 + slot * 8, &Bs[rb * 32]);
    }
    __syncthreads();

    s16x8 af[4], bfr[2];
#pragma unroll
    for (int i = 0; i < 4; ++i) {
      int ar = wr + i * 16 + (lane & 15);
      int as = ((lane >> 4) ^ ((ar >> 1) & 3)) * 8;
      af[i] = *(const s16x8*)&As[ar * 32 + as];
    }
#pragma unroll
    for (int j = 0; j < 2; ++j) {
      int br = wc + j * 16 + (lane & 15);
      int bs = ((lane >> 4) ^ ((br >> 1) & 3)) * 8;
      bfr[j] = *(const s16x8*)&Bs[br * 32 + bs];
    }
#pragma unroll
    for (int i = 0; i < 4; ++i)
#pragma unroll
      for (int j = 0; j < 2; ++j)
        acc[i][j] = __builtin_amdgcn_mfma_f32_16x16x32_bf16(af[i], bfr[j], acc[i][j], 0, 0, 0);
  }

#pragma unroll
  for (int i = 0; i < 4; ++i) {
    int row = bm + wr + i * 16 + ((lane >> 4) << 2);
#pragma unroll
    for (int j = 0; j < 2; ++j) {
      int col = bn + wc + j * 16 + (lane & 15);
      float bv = bias[col];
      float vals[4];
#pragma unroll
      for (int r = 0; r < 4; ++r) vals[r] = acc[i][j][r] + bv;
      if (col < 1024) {  // v_cmp -> f32 kvproj
#pragma unroll
        for (int r = 0; r < 4; ++r)
          kvproj[(size_t)(row + r) * KVP_LD + col] = vals[r];
      } else if (col < 3072) {
        int cc = col - 1024;
        int region = cc >> 9;  // 0 k_slc, 1 v_slc, 2 k_win, 3 v_win
        if ((region & 1) == 0) {
#pragma unroll
          for (int r = 0; r < 4; ++r)
            kvbf[(size_t)(row + r) * KVB_LD + cc] = f2bf(vals[r]);
        } else {
          int mode = region >> 1;
          int kv = (cc >> 7) & 3, d = cc & 127;
          int b = row >> 10;
          u16x4 w4;
#pragma unroll
          for (int r = 0; r < 4; ++r) w4[r] = f2bf(vals[r]);
          *(u16x4*)(VT + (size_t)((b * 4 + kv) * 2 + mode) * 131072 +
                    d * 1024 + (row & 1023)) = w4;
        }
      } else {
#pragma unroll
        for (int r = 0; r < 4; ++r)
          kvproj[(size_t)(row + r) * KVP_LD + (col - 2048)] =
              1.f / (1.f + __expf(-vals[r]));
      }
    }
  }
}

// ---------- RoPE in place on kvbf K slices (bf16; exp2f — continuous path) ----------
__global__ void rope_bf(bf16_t* __restrict__ kvbf) {
  int blk = blockIdx.x;
  int coloff = blockIdx.y << 10;  // 0 (slc K) or 1024 (win K)
  int kv = blk & 3;
  int t = (blk >> 2) & (Tc - 1);
  int b = blk >> 12;
  bf16_t* p = kvbf + (size_t)(b * Tc + t) * KVB_LD + coloff + kv * 128;
  int d = threadIdx.x;
  float inv = exp2f((float)d * (-13.287712379549449f / 64.f));  // 10000^(-d/64)
  float ang = (float)t * inv;
  float s, c;
  sincosf(ang, &s, &c);
  float x1 = bf2f(p[d]), x2 = bf2f(p[d + 64]);
  p[d] = f2bf(x1 * c - x2 * s);
  p[d + 64] = f2bf(x1 * s + x2 * c);
}

// ---------- compress layer1: gathered-A GEMM, split-K x16, k&v merged ----------
__global__ __launch_bounds__(256) void gemm_cmp1(
    const float* __restrict__ kvproj,
    const float* __restrict__ ck1_w, const float* __restrict__ cv1_w,
    float* __restrict__ hk_part, float* __restrict__ hv_part) {
  __shared__ float As[16][68];
  __shared__ float Ws[16][68];
  const int zz = blockIdx.z;
  const bool isv = zz >= 16;
  const int z = zz & 15;
  const int coloff = isv ? 512 : 0;
  const float* W = isv ? cv1_w : ck1_w;
  float* Cpart = isv ? hv_part : hk_part;
  const int bm = blockIdx.y * 64, bn = blockIdx.x * 64;
  const int tid = threadIdx.x;
  const int tx = tid & 15, ty = tid >> 4;
  float acc[4][4] = {{0.f}};
  for (int k0 = z * 256; k0 < z * 256 + 256; k0 += 16) {
#pragma unroll
    for (int i0 = 0; i0 < 4; ++i0) {
      int i = tid + i0 * 256;
      int m = i >> 4, kk = i & 15;
      int gm = bm + m;
      float av = 0.f;
      if (gm < 504) {
        int b = gm / 252, rem = gm % 252;
        int n = rem >> 2, kv = rem & 3;
        int f = k0 + kk;
        int j = f >> 7, d = f & 127;
        av = kvproj[(size_t)(b * Tc + n * 16 + j) * KVP_LD + coloff + kv * 128 + d];
      }
      As[kk][m] = av;
      Ws[kk][m] = W[(size_t)(bn + m) * 4096 + (k0 + kk)];
    }
    __syncthreads();
#pragma unroll
    for (int kk = 0; kk < 16; ++kk) {
      float4 a4 = *reinterpret_cast<const float4*>(&As[kk][ty * 4]);
      float4 w4 = *reinterpret_cast<const float4*>(&Ws[kk][tx * 4]);
      float av[4] = {a4.x, a4.y, a4.z, a4.w};
      float wv[4] = {w4.x, w4.y, w4.z, w4.w};
#pragma unroll
      for (int i = 0; i < 4; ++i)
#pragma unroll
        for (int j = 0; j < 4; ++j) acc[i][j] = fmaf(av[i], wv[j], acc[i][j]);
    }
    __syncthreads();
  }
#pragma unroll
  for (int i = 0; i < 4; ++i) {
    int m = bm + ty * 4 + i;
    if (m >= 504) continue;
#pragma unroll
    for (int j = 0; j < 4; ++j)
      Cpart[(size_t)z * 64512 + (size_t)m * 128 + bn + tx * 4 + j] = acc[i][j];
  }
}

// ---------- bias_adj[o] = b1[o] + block_pos_flat . w1[o,:] ----------
__global__ void bias_adj_kernel(const float* __restrict__ bp,
                                const float* __restrict__ w1k,
                                const float* __restrict__ b1k,
                                const float* __restrict__ w1v,
                                const float* __restrict__ b1v,
                                float* __restrict__ outk,
                                float* __restrict__ outv) {
  __shared__ float red[4];
  const int o = blockIdx.x;
  const float* w1 = blockIdx.y ? w1v : w1k;
  float s = 0.f;
  for (int i = threadIdx.x; i < 4096; i += 256)
    s += bp[i] * w1[(size_t)o * 4096 + i];
#pragma unroll
  for (int off = 32; off; off >>= 1) s += __shfl_xor(s, off);
  if ((threadIdx.x & 63) == 0) red[threadIdx.x >> 6] = s;
  __syncthreads();
  if (threadIdx.x == 0) {
    float t = red[0] + red[1] + red[2] + red[3];
    if (blockIdx.y) outv[o] = t + b1v[o];
    else outk[o] = t + b1k[o];
  }
}

// ---------- reduce 16 partials + bias + gelu, k&v merged ----------
__global__ void reduce_gelu(const float* __restrict__ hk_part,
                            const float* __restrict__ hv_part,
                            const float* __restrict__ bias_k,
                            const float* __restrict__ bias_v,
                            float* __restrict__ hk, float* __restrict__ hv) {
  int gi = blockIdx.x * 256 + threadIdx.x;  // exact: 2*64512/256
  const bool isv = gi >= 64512;
  int i = isv ? gi - 64512 : gi;
  const float* parts = isv ? hv_part : hk_part;
  float s = (isv ? bias_v : bias_k)[i & 127];
#pragma unroll
  for (int z = 0; z < 16; ++z) s += parts[z * 64512 + i];
  (isv ? hv : hk)[i] = geluf(s);
}

// ---------- compress layer2, k&v merged ----------
__global__ __launch_bounds__(256) void gemm_l2(
    const float* __restrict__ hk, const float* __restrict__ w2k,
    const float* __restrict__ b2k, const float* __restrict__ hv,
    const float* __restrict__ w2v, const float* __restrict__ b2v,
    float* __restrict__ k_sum, float* __restrict__ v_sum) {
  __shared__ float As[16][68];
  __shared__ float Ws[16][68];
  const bool isv = blockIdx.z != 0;
  const float* A = isv ? hv : hk;
  const float* W = isv ? w2v : w2k;
  const float* bias = isv ? b2v : b2k;
  float* C = isv ? v_sum : k_sum;
  const int bm = blockIdx.y * 64, bn = blockIdx.x * 64;
  const int tid = threadIdx.x;
  const int tx = tid & 15, ty = tid >> 4;
  float acc[4][4] = {{0.f}};
  for (int k0 = 0; k0 < 128; k0 += 16) {
#pragma unroll
    for (int i0 = 0; i0 < 4; ++i0) {
      int i = tid + i0 * 256;
      int m = i >> 4, kk = i & 15;
      int gm = bm + m;
      As[kk][m] = (gm < 504) ? A[(size_t)gm * 128 + (k0 + kk)] : 0.f;
      Ws[kk][m] = W[(size_t)(bn + m) * 128 + (k0 + kk)];
    }
    __syncthreads();
#pragma unroll
    for (int kk = 0; kk < 16; ++kk) {
      float4 a4 = *reinterpret_cast<const float4*>(&As[kk][ty * 4]);
      float4 w4 = *reinterpret_cast<const float4*>(&Ws[kk][tx * 4]);
      float av[4] = {a4.x, a4.y, a4.z, a4.w};
      float wv[4] = {w4.x, w4.y, w4.z, w4.w};
#pragma unroll
      for (int i = 0; i < 4; ++i)
#pragma unroll
        for (int j = 0; j < 4; ++j) acc[i][j] = fmaf(av[i], wv[j], acc[i][j]);
    }
    __syncthreads();
  }
#pragma unroll
  for (int i = 0; i < 4; ++i) {
    int m = bm + ty * 4 + i;
    if (m >= 504) continue;
#pragma unroll
    for (int j = 0; j < 4; ++j)
      C[(size_t)m * 128 + bn + tx * 4 + j] = acc[i][j] + bias[bn + tx * 4 + j];
  }
}

// ---------- compressed attention + top-k: 8 query tokens per wg ----------
__global__ __launch_bounds__(256) void cmp_attn(
    const float* __restrict__ q, const float* __restrict__ k_sum,
    const float* __restrict__ v_sum, const float* __restrict__ kvproj,
    float* __restrict__ out, unsigned long long* __restrict__ sel) {
  __shared__ __align__(16) float q_s[4][8][128];  // 16KB
  __shared__ __align__(16) float ks[NBc * 128];   // 31.5KB
  __shared__ float p_s[4][8][64];                 // 8KB

  const int wg = blockIdx.x;  // (b*4+kv)*128 + tq
  const int tq = wg & 127;
  const int kv = (wg >> 7) & 3;
  const int b = wg >> 9;
  const int t0 = tq * 8;
  const int tid = threadIdx.x;
  const int lane = tid & 63;
  const int g = tid >> 6;

  // stage q (f32x4): 4 heads x 8 rows x 32 vec = 1024 vec loads
  for (int i = tid; i < 1024; i += 256) {
    int gg = i >> 8, rem = i & 255;
    int r = rem >> 5, v = rem & 31;
    f32x4 q4 = *(const f32x4*)(q +
        (((size_t)b * NQc + gg * NKVc + kv) * Tc + t0 + r) * 128 + v * 4);
    *(f32x4*)&q_s[gg][r][v * 4] = q4;
  }
  {
    const float* kbase = k_sum + (size_t)(b * 252 + kv) * 128;
    for (int i = tid; i < NBc * 32; i += 256) {
      int n = i >> 5, s = i & 31;
      f32x4 v4 = *(const f32x4*)(kbase + (size_t)n * 512 + s * 4);
      *(f32x4*)&ks[n * 128 + ((s ^ (n & 7)) << 2)] = v4;
    }
  }
  __syncthreads();

  float acc[8] = {0.f, 0.f, 0.f, 0.f, 0.f, 0.f, 0.f, 0.f};
  {
    const int lrow = (lane < 63) ? lane : 62;
    const int lx = lrow & 7;
#pragma unroll
    for (int s = 0; s < 32; ++s) {
      f32x4 k4 = *(const f32x4*)&ks[lrow * 128 + ((s ^ lx) << 2)];
#pragma unroll
      for (int r = 0; r < 8; ++r) {
        f32x4 q4 = *(const f32x4*)&q_s[g][r][s * 4];
        acc[r] = fmaf(q4[0], k4[0], acc[r]);
        acc[r] = fmaf(q4[1], k4[1], acc[r]);
        acc[r] = fmaf(q4[2], k4[2], acc[r]);
        acc[r] = fmaf(q4[3], k4[3], acc[r]);
      }
    }
  }
#pragma unroll
  for (int r = 0; r < 8; ++r) {
    const int t = t0 + r;
    const int nvalid = min(t / STRIDEc + 1, NBc);
    const bool valid = (lane < nvalid);
    float sval = valid ? acc[r] * SCALEc : -INFINITY;
    float m = sval;
#pragma unroll
    for (int off = 32; off; off >>= 1) m = fmaxf(m, __shfl_xor(m, off));
    float e = valid ? __expf(sval - m) : 0.f;
    float l = e;
#pragma unroll
    for (int off = 32; off; off >>= 1) l += __shfl_xor(l, off);
    p_s[g][r][lane] = e / fmaxf(l, 1e-9f);
  }
  __syncthreads();

  // top-k: wave g handles rows g and g+4 (lowest-index tie-break == lax.top_k)
#pragma unroll
  for (int half = 0; half < 2; ++half) {
    const int rr = g + half * 4;
    float v = p_s[0][rr][lane] + p_s[1][rr][lane] + p_s[2][rr][lane] + p_s[3][rr][lane];
    if (lane >= NBc) v = -1.f;
    unsigned long long mask = 0ull;
    for (int it = 0; it < TOPNc; ++it) {
      float mx = v;
#pragma unroll
      for (int off = 32; off; off >>= 1) mx = fmaxf(mx, __shfl_xor(mx, off));
      unsigned long long ball = __ballot(v == mx);
      int sl = __ffsll(ball) - 1;
      mask |= 1ull << sl;
      if (lane == sl) v = -1.f;
    }
    if (lane == 0) sel[(((size_t)b * NKVc + kv) << 10) + t0 + rr] = mask;
  }
  {
    const float* vbase = v_sum + (size_t)(b * 252 + kv) * 128;
    for (int i = tid; i < NBc * 32; i += 256) {
      int n = i >> 5, s = i & 31;
      f32x4 v4 = *(const f32x4*)(vbase + (size_t)n * 512 + s * 4);
      *(f32x4*)&ks[n * 128 + ((s ^ (n & 7)) << 2)] = v4;
    }
  }
  __syncthreads();

  const int h = g * NKVc + kv;
  float ox[8], oy[8];
#pragma unroll
  for (int r = 0; r < 8; ++r) { ox[r] = 0.f; oy[r] = 0.f; }
  const int slotd = lane >> 1, wi = (lane & 1) * 2;
  const int nvmax = min((t0 + 7) / STRIDEc + 1, NBc);
  for (int n = 0; n < nvmax; ++n) {
    const float* vp = &ks[n * 128 + (((slotd ^ (n & 7)) << 2) | wi)];
    const float vx = vp[0], vy = vp[1];
#pragma unroll
    for (int r = 0; r < 8; ++r) {
      float pn = p_s[g][r][n];  // 0 for n >= nvalid_r
      ox[r] = fmaf(pn, vx, ox[r]);
      oy[r] = fmaf(pn, vy, oy[r]);
    }
  }
#pragma unroll
  for (int r = 0; r < 8; ++r) {
    const int t = t0 + r;
    const float g0 = kvproj[(size_t)(b * Tc + t) * KVP_LD + 1024 + h * 3];
    size_t obase = ((size_t)(b * NQc + h) * Tc + t) * 128 + lane * 2;
    *(float2*)&out[obase] = make_float2(g0 * ox[r], g0 * oy[r]);
  }
}

// ---------- merged MFMA flash-tile attention (swapped-QK, in-register P) ----------
// R12-proven config: QBLK=32, 8 waves, chunk=64, dbuf, grid 512.
__global__ __launch_bounds__(512, 4) void sparse_attn_mfma(
    const float* __restrict__ q, const bf16_t* __restrict__ kvbf,
    const bf16_t* __restrict__ VT, const float* __restrict__ kvproj,
    const unsigned long long* __restrict__ sel,
    float* __restrict__ out, float* __restrict__ out2) {
  __shared__ bf16_t KsB[2][64 * 128];   // [s][d], swz ^((s&7)<<4) via pre-swz source
  __shared__ bf16_t VtB[2][128 * 64];   // [d][s], swz ^(((d>>1)&7)<<4)

  const int wgi = blockIdx.x;
  const int b = wgi & 1;
  const int kv = (wgi >> 1) & 3;
  const int Y = (wgi >> 3) & 31;
  const int mode = (wgi >> 8) & 1;
  const int tt = mode ? Y : 31 - Y;
  const int t0 = tt * 32;
  const int tid = threadIdx.x, lane = tid & 63;
  const int wv = tid >> 6;   // 0..7
  const int g = wv & 3;      // head
  const int half = wv >> 2;  // row-half
  const int t0h = t0 + half * 16;
  const int h = g * NKVc + kv;
  const int lr = lane >> 4;
  const int lc = lane & 15;
  const int tL = t0h + lc;   // this lane's softmax column (query row)

  s16x8 aq[4];
  {
    const float* qrow = q + (((size_t)(b * NQc + h) * Tc) + tL) * 128;
#pragma unroll
    for (int ks = 0; ks < 4; ++ks) {
      f32x4 lo = *(const f32x4*)(qrow + ks * 32 + lr * 8);
      f32x4 hi = *(const f32x4*)(qrow + ks * 32 + lr * 8 + 4);
      s16x8 v;
#pragma unroll
      for (int e = 0; e < 4; ++e) {
        v[e] = (short)f2bf(lo[e]);
        v[e + 4] = (short)f2bf(hi[e]);
      }
      aq[ks] = v;
    }
  }

  unsigned long long hm = ~0ull;
  unsigned long long um = ~0ull;
  int c0;
  const int c1 = (t0 + 31) >> 6;
  const unsigned long long* sb = sel + ((size_t)(b * NKVc + kv) << 10);
  if (mode == 0) {
    unsigned long long bm = sb[tL];
    hm = bm | (bm << 1);
    unsigned long long uu = 0ull;
    if (lane < 32) {
      unsigned long long b2 = sb[t0 + lane];
      uu = b2 | (b2 << 1);
    }
#pragma unroll
    for (int off = 32; off; off >>= 1) uu |= __shfl_xor(uu, off);
    um = uu;
    c0 = (__ffsll(um) - 1) >> 2;
  } else {
    int lo = t0 - (WINc - 1);
    c0 = (lo > 0 ? lo : 0) >> 6;
  }

  float run_m = -INFINITY, run_l = 0.f;
  f32x4 acc_o[8];
#pragma unroll
  for (int j = 0; j < 8; ++j) acc_o[j] = 0.f;

  const bf16_t* kb = kvbf + (mode << 10) + kv * 128;
  const bf16_t* vt = VT + (size_t)((b * 4 + kv) * 2 + mode) * 131072;
  const size_t rbase = (size_t)b * Tc;

  auto STAGE = [&](int bufi, int c) {
    const int s0 = c * 64;
#pragma unroll
    for (int p = 0; p < 2; ++p) {
      int o = p * 512 + tid;
      int s = o >> 4, sl = o & 15;
      int slot = sl ^ (s & 7);
      load_lds16(kb + (rbase + s0 + s) * KVB_LD + slot * 8,
                 (char*)&KsB[bufi][0] + (p * 512 + wv * 64) * 16);
    }
#pragma unroll
    for (int p = 0; p < 2; ++p) {
      int o = p * 512 + tid;
      int d = o >> 3, sl = o & 7;
      int slot = sl ^ ((d >> 1) & 7);
      load_lds16(vt + (size_t)d * 1024 + s0 + slot * 8,
                 (char*)&VtB[bufi][0] + (p * 512 + wv * 64) * 16);
    }
  };

  int c = c0;
  STAGE(0, c);
  int buf = 0;
  while (true) {
    int cn = c + 1;
    if (mode == 0)
      while (cn <= c1 && ((um >> (4 * cn)) & 0xFull) == 0ull) ++cn;
    __syncthreads();
    if (cn <= c1) STAGE(buf ^ 1, cn);

    const int s0 = c * 64;
    const char* KsP = (const char*)&KsB[buf][0];
    const char* VtP = (const char*)&VtB[buf][0];

    f32x4 accs[4];
#pragma unroll
    for (int j = 0; j < 4; ++j) accs[j] = 0.f;
    __builtin_amdgcn_s_setprio(1);
#pragma unroll
    for (int ks = 0; ks < 4; ++ks) {
      s16x8 bk[4];
#pragma unroll
      for (int j = 0; j < 4; ++j) {
        int sB = j * 16 + lc;
        bk[j] = *(const s16x8*)(KsP +
                                ((sB * 256 + (ks * 4 + lr) * 16) ^ ((sB & 7) << 4)));
      }
#pragma unroll
      for (int j = 0; j < 4; ++j)
        accs[j] = __builtin_amdgcn_mfma_f32_16x16x32_bf16(bk[j], aq[ks], accs[j], 0, 0, 0);
    }
    __builtin_amdgcn_s_setprio(0);

    float ev[4][4];
    float mx = -INFINITY;
#pragma unroll
    for (int j = 0; j < 4; ++j)
#pragma unroll
      for (int r = 0; r < 4; ++r) {
        int s = s0 + j * 16 + lr * 4 + r;
        bool att;
        if (mode == 0) att = (s <= tL) && ((hm >> (s >> 4)) & 1ull);
        else att = (s <= tL) && (tL - s < WINc);
        float sv = att ? accs[j][r] * SCALEc : -INFINITY;
        ev[j][r] = sv;
        mx = fmaxf(mx, sv);
      }
    mx = fmaxf(mx, __shfl_xor(mx, 16));
    mx = fmaxf(mx, __shfl_xor(mx, 32));
    const bool defer = __all(mx <= run_m + 8.f);
    float nm = run_m;
    if (!defer) {
      nm = fmaxf(run_m, mx);
      const float resc = (run_m == -INFINITY) ? 0.f : __expf(run_m - nm);
      float rs[4];
#pragma unroll
      for (int r = 0; r < 4; ++r) rs[r] = __shfl(resc, lr * 16 + lr * 4 + r);
#pragma unroll
      for (int jo = 0; jo < 8; ++jo)
#pragma unroll
        for (int r = 0; r < 4; ++r) acc_o[jo][r] *= rs[r];
      run_l *= resc;
      run_m = nm;
    }
    float cl = 0.f;
#pragma unroll
    for (int j = 0; j < 4; ++j)
#pragma unroll
      for (int r = 0; r < 4; ++r) {
        float e = (ev[j][r] == -INFINITY) ? 0.f : __expf(ev[j][r] - nm);
        ev[j][r] = e;
        cl += e;
      }
    cl += __shfl_xor(cl, 16);
    cl += __shfl_xor(cl, 32);
    run_l += cl;

    unsigned int pw[4][2];
#pragma unroll
    for (int j = 0; j < 4; ++j) {
      pw[j][0] = ((unsigned int)f2bf(ev[j][1]) << 16) | f2bf(ev[j][0]);
      pw[j][1] = ((unsigned int)f2bf(ev[j][3]) << 16) | f2bf(ev[j][2]);
    }

    s16x8 ap[2];
#pragma unroll
    for (int k2 = 0; k2 < 2; ++k2) {
      u32x4 words;
#pragma unroll
      for (int w = 0; w < 4; ++w) {
        int src = ((lr & 1) * 2 + (w >> 1)) * 16 + lc;
        unsigned int a0 = __shfl((int)pw[2 * k2][w & 1], src);
        unsigned int a1 = __shfl((int)pw[2 * k2 + 1][w & 1], src);
        words[w] = (lr >> 1) ? a1 : a0;
      }
      ap[k2] = __builtin_bit_cast(s16x8, words);
    }

    __builtin_amdgcn_s_setprio(1);
#pragma unroll
    for (int k2 = 0; k2 < 2; ++k2) {
#pragma unroll
      for (int jo = 0; jo < 8; ++jo) {
        int d = jo * 16 + lc;
        s16x8 bv = *(const s16x8*)(VtP +
                                   ((d * 128 + k2 * 64 + lr * 16) ^ (((d >> 1) & 7) << 4)));
        acc_o[jo] = __builtin_amdgcn_mfma_f32_16x16x32_bf16(ap[k2], bv, acc_o[jo], 0, 0, 0);
      }
    }
    __builtin_amdgcn_s_setprio(0);

    if (cn > c1) break;
    buf ^= 1;
    c = cn;
  }

  float rl[4];
#pragma unroll
  for (int r = 0; r < 4; ++r) rl[r] = __shfl(run_l, lr * 16 + lr * 4 + r);
#pragma unroll
  for (int r = 0; r < 4; ++r) {
    const int t = t0h + lr * 4 + r;
    const float gg = kvproj[(rbase + t) * KVP_LD + 1024 + h * 3 + 1 + mode];
    const float sc = gg / fmaxf(rl[r], 1e-9f);
    const size_t ob = ((size_t)(b * NQc + h) * Tc + t) * 128;
#pragma unroll
    for (int jo = 0; jo < 8; ++jo) {
      size_t oi = ob + jo * 16 + lc;
      float v = acc_o[jo][r] * sc;
      if (mode == 0) out[oi] += v;
      else out2[oi] = v;
    }
  }
}

// ---------- out += out2 (float4) ----------
__global__ void add_out(float* __restrict__ out, const float* __restrict__ out2) {
  size_t i = (size_t)blockIdx.x * 256 + threadIdx.x;  // exact: 1048576/256 = 4096
  f32x4 a = ((const f32x4*)out)[i];
  f32x4 bv = ((const f32x4*)out2)[i];
  ((f32x4*)out)[i] = a + bv;
}

extern "C" void kernel_launch(void* const* d_in, const int* in_sizes, int n_in,
                              void* d_out, int out_size, void* d_ws, size_t ws_size,
                              hipStream_t stream) {
  const float* x = (const float*)d_in[0];
  const float* q = (const float*)d_in[1];
  const float* gate_w = (const float*)d_in[2];
  const float* gate_b = (const float*)d_in[3];
  const float* wk_cmp = (const float*)d_in[4];
  const float* wv_cmp = (const float*)d_in[5];
  const float* wk_slc = (const float*)d_in[6];
  const float* wv_slc = (const float*)d_in[7];
  const float* wk_win = (const float*)d_in[8];
  const float* wv_win = (const float*)d_in[9];
  const float* block_pos = (const float*)d_in[10];
  const float* ck1_w = (const float*)d_in[11];
  const float* ck1_b = (const float*)d_in[12];
  const float* ck2_w = (const float*)d_in[13];
  const float* ck2_b = (const float*)d_in[14];
  const float* cv1_w = (const float*)d_in[15];
  const float* cv1_b = (const float*)d_in[16];
  const float* cv2_w = (const float*)d_in[17];
  const float* cv2_b = (const float*)d_in[18];
  float* out = (float*)d_out;

  char* wsp = (char*)d_ws;
  float* kvproj = (float*)wsp;
  bf16_t* kvbf = (bf16_t*)(wsp + 10485760);
  float* part = (float*)(wsp + 10485760);     // k_cmp partials, dead before kvbf written
  bf16_t* VT = (bf16_t*)(wsp + 18874368);
  bf16_t* xbf = (bf16_t*)(wsp + 23068672);
  bf16_t* xlo = (bf16_t*)(wsp + 31457280);
  bf16_t* Wk_hi = (bf16_t*)(wsp + 39845888);
  bf16_t* Wk_lo = (bf16_t*)(wsp + 41943040);
  bf16_t* Wcat = (bf16_t*)(wsp + 31457280);   // overwrites xlo/Wk after gemm_prec
  float* bias_cat = (float*)(wsp + 44040192);
  unsigned long long* selB = (unsigned long long*)(wsp + 44052992);
  float* hk = (float*)(wsp + 44118528);
  float* hv = (float*)(wsp + 44376576);
  float* k_sum = (float*)(wsp + 44634624);
  float* v_sum = (float*)(wsp + 44892672);
  float* bias_k = (float*)(wsp + 45150720);
  float* bias_v = (float*)(wsp + 45151232);

  float* hk_part = (float*)(wsp + 23068672);  // xbf region (dead after GEMMs)
  float* hv_part = (float*)(wsp + 27197440);
  float* out2 = (float*)(wsp + 23068672);     // 16 MB (parts/Wcat dead by then)

  dim3 blk256(256);

  prep_kernel<<<5120, blk256, 0, stream>>>(x, xbf, xlo, wk_cmp, Wk_hi, Wk_lo);

  gemm_prec<<<dim3(8, 16, 2), blk256, 0, stream>>>(xbf, xlo, Wk_hi, Wk_lo, part);
  rope_k_fused2<<<Bc * Tc * NKVc, 64, 0, stream>>>(part, kvproj);

  build_wcat<<<21504, blk256, 0, stream>>>(wv_cmp, wk_slc, wv_slc, wk_win,
                                           wv_win, gate_w, gate_b, Wcat, bias_cat);
  gemm_mfma<<<dim3(42, 16), blk256, 0, stream>>>(
      xbf, 2048, Wcat, 2048, kvproj, kvbf, VT, bias_cat, 2048);

  rope_bf<<<dim3(Bc * Tc * NKVc, 2), 64, 0, stream>>>(kvbf);

  bias_adj_kernel<<<dim3(128, 2), blk256, 0, stream>>>(block_pos, ck1_w, ck1_b,
                                                       cv1_w, cv1_b, bias_k, bias_v);
  gemm_cmp1<<<dim3(2, 8, 32), blk256, 0, stream>>>(kvproj, ck1_w, cv1_w,
                                                   hk_part, hv_part);
  reduce_gelu<<<504, blk256, 0, stream>>>(hk_part, hv_part, bias_k, bias_v, hk, hv);
  gemm_l2<<<dim3(2, 8, 2), blk256, 0, stream>>>(hk, ck2_w, ck2_b, hv, cv2_w,
                                                cv2_b, k_sum, v_sum);

  cmp_attn<<<1024, blk256, 0, stream>>>(q, k_sum, v_sum, kvproj, out, selB);
  sparse_attn_mfma<<<512, dim3(512), 0, stream>>>(q, kvbf, VT, kvproj, selB, out, out2);
  add_out<<<4096, blk256, 0, stream>>>(out, out2);
}

// Round 16
// 298.255 us; speedup vs baseline: 1.1961x; 1.0675x over previous
//
#include <hip/hip_runtime.h>
#include <hip/hip_bf16.h>
#include <math.h>

#define Bc 2
#define Tc 1024
#define DMc 2048
#define NQc 16
#define NKVc 4
#define DHc 128
#define BLKc 32
#define STRIDEc 16
#define TOPNc 16
#define WINc 512
#define NREPc 4
#define NBc 63
#define SCALEc 0.08838834764831843f
#define KVP_LD 1280   // kvproj f32: 0..511 k_cmp | 512..1023 v_cmp | 1024..1071 gates | pad
#define KVB_LD 2048   // kvbf bf16: 0..511 k_slc | 1024..1535 k_win (v slices go to VT)

typedef unsigned short bf16_t;
typedef short s16x8 __attribute__((ext_vector_type(8)));
typedef float f32x4 __attribute__((ext_vector_type(4)));
typedef unsigned short u16x4 __attribute__((ext_vector_type(4)));
typedef unsigned int u32x4 __attribute__((ext_vector_type(4)));

__device__ __forceinline__ unsigned short f2bf(float f) {
  unsigned int u = __float_as_uint(f);
  u += 0x7fffu + ((u >> 16) & 1u);
  return (unsigned short)(u >> 16);
}
__device__ __forceinline__ float bf2f(unsigned short h) {
  return __uint_as_float((unsigned int)h << 16);
}
__device__ __forceinline__ float geluf(float x) {
  return 0.5f * x * (1.0f + erff(x * 0.7071067811865476f));
}
__device__ __forceinline__ void load_lds16(const void* g, void* l) {
  __builtin_amdgcn_global_load_lds(
      (const __attribute__((address_space(1))) void*)g,
      (__attribute__((address_space(3))) void*)l, 16, 0, 0);
}

// ---------- prep (float4): x->hi/lo, wk_cmp->hi/lo ----------
__global__ void prep_kernel(const float* __restrict__ x, bf16_t* __restrict__ xbf,
                            bf16_t* __restrict__ xlo,
                            const float* __restrict__ wk_cmp,
                            bf16_t* __restrict__ Wk_hi, bf16_t* __restrict__ Wk_lo) {
  size_t gid = (size_t)blockIdx.x * 256 + threadIdx.x;  // exact: 1310720/256 = 5120
  const float* src;
  bf16_t *dh, *dl;
  size_t i;
  if (gid < 1048576) {
    i = gid * 4;
    src = x; dh = xbf; dl = xlo;
  } else {
    i = (gid - 1048576) * 4;
    src = wk_cmp; dh = Wk_hi; dl = Wk_lo;
  }
  f32x4 f = *(const f32x4*)(src + i);
  u16x4 h, l;
#pragma unroll
  for (int e = 0; e < 4; ++e) {
    h[e] = f2bf(f[e]);
    l[e] = f2bf(f[e] - bf2f(h[e]));
  }
  *(u16x4*)(dh + i) = h;
  *(u16x4*)(dl + i) = l;
}

// ---------- concat weights rows 512..3199 into bf16 Wcat ----------
__global__ void build_wcat(
    const float* __restrict__ wv_cmp, const float* __restrict__ wk_slc,
    const float* __restrict__ wv_slc, const float* __restrict__ wk_win,
    const float* __restrict__ wv_win, const float* __restrict__ gate_w,
    const float* __restrict__ gate_b, bf16_t* __restrict__ Wcat,
    float* __restrict__ bias_cat) {
  size_t i = (size_t)blockIdx.x * 256 + threadIdx.x;  // exact: 2688*2048/256
  int rr = (int)(i >> 11), c = (int)(i & 2047);
  int r = rr + 512;
  float v = 0.f;
  if (r < 3072) {
    int blk = r >> 9;  // 1..5
    size_t o = (size_t)(r & 511) * 2048 + c;
    if (blk == 1) v = wv_cmp[o];
    else if (blk == 2) v = wk_slc[o];
    else if (blk == 3) v = wv_slc[o];
    else if (blk == 4) v = wk_win[o];
    else v = wv_win[o];
  } else if (r < 3120) {
    v = gate_w[(size_t)(r - 3072) * 2048 + c];
  }
  Wcat[i] = f2bf(v);
  if (c == 0) bias_cat[r] = (r >= 3072 && r < 3120) ? gate_b[r - 3072] : 0.f;
}

// ---------- hi/lo split-bf16 MFMA GEMM for k_cmp, BM=128 BN=64 BK=64, split-K x2 ----------
__global__ __launch_bounds__(256) void gemm_prec(
    const bf16_t* __restrict__ A, const bf16_t* __restrict__ Alo,
    const bf16_t* __restrict__ Bw, const bf16_t* __restrict__ Blo,
    float* __restrict__ part) {
  __shared__ bf16_t As[2 * 128 * 64];  // hi at 0, lo at 8192 (elements)
  __shared__ bf16_t Bs[2 * 64 * 64];   // hi at 0, lo at 4096
  const int z = blockIdx.z;
  const int bm = blockIdx.y * 128, bnw = blockIdx.x * 64;
  const int tid = threadIdx.x, lane = tid & 63, w = tid >> 6;
  const int wr = (w >> 1) * 64, wc = (w & 1) * 32;
  const int kbase = z * 1024;

  f32x4 acc[4][2];
#pragma unroll
  for (int i = 0; i < 4; ++i)
#pragma unroll
    for (int j = 0; j < 2; ++j) acc[i][j] = 0.f;

  for (int k0 = kbase; k0 < kbase + 1024; k0 += 64) {
    __syncthreads();
    // A hi/lo: 128 rows x 8 slots of 16B = 1024 slots each, 4 insts/thread each
#pragma unroll
    for (int p = 0; p < 4; ++p) {
      int pos = p * 256 + tid;
      int row = pos >> 3, sl = pos & 7;
      int slot = sl ^ (row & 7);  // pre-swizzled source, linear dest (G21)
      const char* dst = (const char*)0 + (p * 256 + w * 64) * 16;
      load_lds16(A + (size_t)(bm + row) * 2048 + k0 + slot * 8,
                 (char*)As + (p * 256 + w * 64) * 16);
      load_lds16(Alo + (size_t)(bm + row) * 2048 + k0 + slot * 8,
                 (char*)As + 16384 + (p * 256 + w * 64) * 16);
      (void)dst;
    }
    // B hi/lo: 64 rows x 8 slots = 512 slots each, 2 insts/thread each
#pragma unroll
    for (int p = 0; p < 2; ++p) {
      int pos = p * 256 + tid;
      int row = pos >> 3, sl = pos & 7;
      int slot = sl ^ (row & 7);
      load_lds16(Bw + (size_t)(bnw + row) * 2048 + k0 + slot * 8,
                 (char*)Bs + (p * 256 + w * 64) * 16);
      load_lds16(Blo + (size_t)(bnw + row) * 2048 + k0 + slot * 8,
                 (char*)Bs + 8192 + (p * 256 + w * 64) * 16);
    }
    __syncthreads();

    const int lr = lane >> 4;
#pragma unroll
    for (int kk = 0; kk < 2; ++kk) {
      s16x8 af[4], afl[4], bfr[2], bfl[2];
#pragma unroll
      for (int i = 0; i < 4; ++i) {
        int ar = wr + i * 16 + (lane & 15);
        int s8 = ((kk * 4 + lr) ^ (ar & 7)) * 8;
        af[i] = *(const s16x8*)&As[ar * 64 + s8];
        afl[i] = *(const s16x8*)&As[8192 + ar * 64 + s8];
      }
#pragma unroll
      for (int j = 0; j < 2; ++j) {
        int br = wc + j * 16 + (lane & 15);
        int s8 = ((kk * 4 + lr) ^ (br & 7)) * 8;
        bfr[j] = *(const s16x8*)&Bs[br * 64 + s8];
        bfl[j] = *(const s16x8*)&Bs[4096 + br * 64 + s8];
      }
#pragma unroll
      for (int i = 0; i < 4; ++i)
#pragma unroll
        for (int j = 0; j < 2; ++j) {
          acc[i][j] = __builtin_amdgcn_mfma_f32_16x16x32_bf16(afl[i], bfr[j], acc[i][j], 0, 0, 0);
          acc[i][j] = __builtin_amdgcn_mfma_f32_16x16x32_bf16(af[i], bfl[j], acc[i][j], 0, 0, 0);
          acc[i][j] = __builtin_amdgcn_mfma_f32_16x16x32_bf16(af[i], bfr[j], acc[i][j], 0, 0, 0);
        }
    }
  }

  const int lr = lane >> 4;
  float* pz = part + (size_t)z * 1048576;
#pragma unroll
  for (int i = 0; i < 4; ++i) {
    int row = bm + wr + i * 16 + lr * 4;
#pragma unroll
    for (int j = 0; j < 2; ++j) {
      int col = bnw + wc + j * 16 + (lane & 15);
#pragma unroll
      for (int r = 0; r < 4; ++r)
        pz[(size_t)(row + r) * 512 + col] = acc[i][j][r];
    }
  }
}

// ---------- reduce 2 k_cmp partials + RoPE -> kvproj cols 0..511 ----------
__global__ void rope_k_fused2(const float* __restrict__ part,
                              float* __restrict__ kvproj) {
  int blk = blockIdx.x;  // (b*T+t)*KV+kv
  int kv = blk & 3;
  int t = (blk >> 2) & (Tc - 1);
  int b = blk >> 12;
  int d = threadIdx.x;  // 0..63
  size_t base = (size_t)(b * Tc + t) * 512 + kv * 128;
  float x1 = part[base + d] + part[1048576 + base + d];
  float x2 = part[base + d + 64] + part[1048576 + base + d + 64];
  float inv = powf(10000.f, -(float)d * (1.f / 64.f));
  float ang = (float)t * inv;
  float s, c;
  sincosf(ang, &s, &c);
  float* p = kvproj + (size_t)(b * Tc + t) * KVP_LD + kv * 128;
  p[d] = x1 * c - x2 * s;
  p[d + 64] = x1 * s + x2 * c;
}

// ---------- bf16 MFMA GEMM: cols 512..3199, BM=128 BN=64 BK=64 ----------
__global__ __launch_bounds__(256) void gemm_mfma(
    const bf16_t* __restrict__ A, int lda,
    const bf16_t* __restrict__ Bw, int ldb,
    float* __restrict__ kvproj, bf16_t* __restrict__ kvbf,
    bf16_t* __restrict__ VT, const float* __restrict__ bias, int K) {
  __shared__ bf16_t As[128 * 64];  // 16KB
  __shared__ bf16_t Bs[64 * 64];   // 8KB
  const int bm = blockIdx.y * 128, bnw = blockIdx.x * 64, bn = 512 + bnw;
  const int tid = threadIdx.x, lane = tid & 63, w = tid >> 6;
  const int wr = (w >> 1) * 64, wc = (w & 1) * 32;
  const int lr = lane >> 4;

  f32x4 acc[4][2];
#pragma unroll
  for (int i = 0; i < 4; ++i)
#pragma unroll
    for (int j = 0; j < 2; ++j) acc[i][j] = 0.f;

  for (int k0 = 0; k0 < K; k0 += 64) {
    __syncthreads();
    // A: 128 rows x 8 slots of 16B = 1024 slots, 4 insts/thread
#pragma unroll
    for (int p = 0; p < 4; ++p) {
      int pos = p * 256 + tid;
      int row = pos >> 3, sl = pos & 7;
      int slot = sl ^ (row & 7);  // pre-swizzled source, linear dest (G21)
      load_lds16(A + (size_t)(bm + row) * lda + k0 + slot * 8,
                 (char*)As + (p * 256 + w * 64) * 16);
    }
    // B: 64 rows x 8 slots = 512 slots, 2 insts/thread
#pragma unroll
    for (int p = 0; p < 2; ++p) {
      int pos = p * 256 + tid;
      int row = pos >> 3, sl = pos & 7;
      int slot = sl ^ (row & 7);
      load_lds16(Bw + (size_t)(bnw + row) * ldb + k0 + slot * 8,
                 (char*)Bs + (p * 256 + w * 64) * 16);
    }
    __syncthreads();

#pragma unroll
    for (int kk = 0; kk < 2; ++kk) {
      s16x8 af[4], bfr[2];
#pragma unroll
      for (int i = 0; i < 4; ++i) {
        int ar = wr + i * 16 + (lane & 15);
        int s8 = ((kk * 4 + lr) ^ (ar & 7)) * 8;
        af[i] = *(const s16x8*)&As[ar * 64 + s8];
      }
#pragma unroll
      for (int j = 0; j < 2; ++j) {
        int br = wc + j * 16 + (lane & 15);
        int s8 = ((kk * 4 + lr) ^ (br & 7)) * 8;
        bfr[j] = *(const s16x8*)&Bs[br * 64 + s8];
      }
#pragma unroll
      for (int i = 0; i < 4; ++i)
#pragma unroll
        for (int j = 0; j < 2; ++j)
          acc[i][j] = __builtin_amdgcn_mfma_f32_16x16x32_bf16(af[i], bfr[j], acc[i][j], 0, 0, 0);
    }
  }

#pragma unroll
  for (int i = 0; i < 4; ++i) {
    int row = bm + wr + i * 16 + lr * 4;
#pragma unroll
    for (int j = 0; j < 2; ++j) {
      int col = bn + wc + j * 16 + (lane & 15);
      float bv = bias[col];
      float vals[4];
#pragma unroll
      for (int r = 0; r < 4; ++r) vals[r] = acc[i][j][r] + bv;
      if (col < 1024) {  // v_cmp -> f32 kvproj
#pragma unroll
        for (int r = 0; r < 4; ++r)
          kvproj[(size_t)(row + r) * KVP_LD + col] = vals[r];
      } else if (col < 3072) {
        int cc = col - 1024;
        int region = cc >> 9;  // 0 k_slc, 1 v_slc, 2 k_win, 3 v_win
        if ((region & 1) == 0) {
#pragma unroll
          for (int r = 0; r < 4; ++r)
            kvbf[(size_t)(row + r) * KVB_LD + cc] = f2bf(vals[r]);
        } else {
          int mode = region >> 1;
          int kv = (cc >> 7) & 3, d = cc & 127;
          int b = row >> 10;
          u16x4 w4;
#pragma unroll
          for (int r = 0; r < 4; ++r) w4[r] = f2bf(vals[r]);
          *(u16x4*)(VT + (size_t)((b * 4 + kv) * 2 + mode) * 131072 +
                    d * 1024 + (row & 1023)) = w4;
        }
      } else {
#pragma unroll
        for (int r = 0; r < 4; ++r)
          kvproj[(size_t)(row + r) * KVP_LD + (col - 2048)] =
              1.f / (1.f + __expf(-vals[r]));
      }
    }
  }
}

// ---------- RoPE in place on kvbf K slices (bf16; exp2f — continuous path) ----------
__global__ void rope_bf(bf16_t* __restrict__ kvbf) {
  int blk = blockIdx.x;
  int coloff = blockIdx.y << 10;  // 0 (slc K) or 1024 (win K)
  int kv = blk & 3;
  int t = (blk >> 2) & (Tc - 1);
  int b = blk >> 12;
  bf16_t* p = kvbf + (size_t)(b * Tc + t) * KVB_LD + coloff + kv * 128;
  int d = threadIdx.x;
  float inv = exp2f((float)d * (-13.287712379549449f / 64.f));  // 10000^(-d/64)
  float ang = (float)t * inv;
  float s, c;
  sincosf(ang, &s, &c);
  float x1 = bf2f(p[d]), x2 = bf2f(p[d + 64]);
  p[d] = f2bf(x1 * c - x2 * s);
  p[d + 64] = f2bf(x1 * s + x2 * c);
}

// ---------- compress layer1: gathered-A GEMM, split-K x16, k&v merged ----------
__global__ __launch_bounds__(256) void gemm_cmp1(
    const float* __restrict__ kvproj,
    const float* __restrict__ ck1_w, const float* __restrict__ cv1_w,
    float* __restrict__ hk_part, float* __restrict__ hv_part) {
  __shared__ float As[16][68];
  __shared__ float Ws[16][68];
  const int zz = blockIdx.z;
  const bool isv = zz >= 16;
  const int z = zz & 15;
  const int coloff = isv ? 512 : 0;
  const float* W = isv ? cv1_w : ck1_w;
  float* Cpart = isv ? hv_part : hk_part;
  const int bm = blockIdx.y * 64, bn = blockIdx.x * 64;
  const int tid = threadIdx.x;
  const int tx = tid & 15, ty = tid >> 4;
  float acc[4][4] = {{0.f}};
  for (int k0 = z * 256; k0 < z * 256 + 256; k0 += 16) {
#pragma unroll
    for (int i0 = 0; i0 < 4; ++i0) {
      int i = tid + i0 * 256;
      int m = i >> 4, kk = i & 15;
      int gm = bm + m;
      float av = 0.f;
      if (gm < 504) {
        int b = gm / 252, rem = gm % 252;
        int n = rem >> 2, kv = rem & 3;
        int f = k0 + kk;
        int j = f >> 7, d = f & 127;
        av = kvproj[(size_t)(b * Tc + n * 16 + j) * KVP_LD + coloff + kv * 128 + d];
      }
      As[kk][m] = av;
      Ws[kk][m] = W[(size_t)(bn + m) * 4096 + (k0 + kk)];
    }
    __syncthreads();
#pragma unroll
    for (int kk = 0; kk < 16; ++kk) {
      float4 a4 = *reinterpret_cast<const float4*>(&As[kk][ty * 4]);
      float4 w4 = *reinterpret_cast<const float4*>(&Ws[kk][tx * 4]);
      float av[4] = {a4.x, a4.y, a4.z, a4.w};
      float wv[4] = {w4.x, w4.y, w4.z, w4.w};
#pragma unroll
      for (int i = 0; i < 4; ++i)
#pragma unroll
        for (int j = 0; j < 4; ++j) acc[i][j] = fmaf(av[i], wv[j], acc[i][j]);
    }
    __syncthreads();
  }
#pragma unroll
  for (int i = 0; i < 4; ++i) {
    int m = bm + ty * 4 + i;
    if (m >= 504) continue;
#pragma unroll
    for (int j = 0; j < 4; ++j)
      Cpart[(size_t)z * 64512 + (size_t)m * 128 + bn + tx * 4 + j] = acc[i][j];
  }
}

// ---------- bias_adj[o] = b1[o] + block_pos_flat . w1[o,:] ----------
__global__ void bias_adj_kernel(const float* __restrict__ bp,
                                const float* __restrict__ w1k,
                                const float* __restrict__ b1k,
                                const float* __restrict__ w1v,
                                const float* __restrict__ b1v,
                                float* __restrict__ outk,
                                float* __restrict__ outv) {
  __shared__ float red[4];
  const int o = blockIdx.x;
  const float* w1 = blockIdx.y ? w1v : w1k;
  float s = 0.f;
  for (int i = threadIdx.x; i < 4096; i += 256)
    s += bp[i] * w1[(size_t)o * 4096 + i];
#pragma unroll
  for (int off = 32; off; off >>= 1) s += __shfl_xor(s, off);
  if ((threadIdx.x & 63) == 0) red[threadIdx.x >> 6] = s;
  __syncthreads();
  if (threadIdx.x == 0) {
    float t = red[0] + red[1] + red[2] + red[3];
    if (blockIdx.y) outv[o] = t + b1v[o];
    else outk[o] = t + b1k[o];
  }
}

// ---------- reduce 16 partials + bias + gelu, k&v merged ----------
__global__ void reduce_gelu(const float* __restrict__ hk_part,
                            const float* __restrict__ hv_part,
                            const float* __restrict__ bias_k,
                            const float* __restrict__ bias_v,
                            float* __restrict__ hk, float* __restrict__ hv) {
  int gi = blockIdx.x * 256 + threadIdx.x;  // exact: 2*64512/256
  const bool isv = gi >= 64512;
  int i = isv ? gi - 64512 : gi;
  const float* parts = isv ? hv_part : hk_part;
  float s = (isv ? bias_v : bias_k)[i & 127];
#pragma unroll
  for (int z = 0; z < 16; ++z) s += parts[z * 64512 + i];
  (isv ? hv : hk)[i] = geluf(s);
}

// ---------- compress layer2, k&v merged ----------
__global__ __launch_bounds__(256) void gemm_l2(
    const float* __restrict__ hk, const float* __restrict__ w2k,
    const float* __restrict__ b2k, const float* __restrict__ hv,
    const float* __restrict__ w2v, const float* __restrict__ b2v,
    float* __restrict__ k_sum, float* __restrict__ v_sum) {
  __shared__ float As[16][68];
  __shared__ float Ws[16][68];
  const bool isv = blockIdx.z != 0;
  const float* A = isv ? hv : hk;
  const float* W = isv ? w2v : w2k;
  const float* bias = isv ? b2v : b2k;
  float* C = isv ? v_sum : k_sum;
  const int bm = blockIdx.y * 64, bn = blockIdx.x * 64;
  const int tid = threadIdx.x;
  const int tx = tid & 15, ty = tid >> 4;
  float acc[4][4] = {{0.f}};
  for (int k0 = 0; k0 < 128; k0 += 16) {
#pragma unroll
    for (int i0 = 0; i0 < 4; ++i0) {
      int i = tid + i0 * 256;
      int m = i >> 4, kk = i & 15;
      int gm = bm + m;
      As[kk][m] = (gm < 504) ? A[(size_t)gm * 128 + (k0 + kk)] : 0.f;
      Ws[kk][m] = W[(size_t)(bn + m) * 128 + (k0 + kk)];
    }
    __syncthreads();
#pragma unroll
    for (int kk = 0; kk < 16; ++kk) {
      float4 a4 = *reinterpret_cast<const float4*>(&As[kk][ty * 4]);
      float4 w4 = *reinterpret_cast<const float4*>(&Ws[kk][tx * 4]);
      float av[4] = {a4.x, a4.y, a4.z, a4.w};
      float wv[4] = {w4.x, w4.y, w4.z, w4.w};
#pragma unroll
      for (int i = 0; i < 4; ++i)
#pragma unroll
        for (int j = 0; j < 4; ++j) acc[i][j] = fmaf(av[i], wv[j], acc[i][j]);
    }
    __syncthreads();
  }
#pragma unroll
  for (int i = 0; i < 4; ++i) {
    int m = bm + ty * 4 + i;
    if (m >= 504) continue;
#pragma unroll
    for (int j = 0; j < 4; ++j)
      C[(size_t)m * 128 + bn + tx * 4 + j] = acc[i][j] + bias[bn + tx * 4 + j];
  }
}

// ---------- compressed attention + top-k: 8 query tokens per wg ----------
__global__ __launch_bounds__(256) void cmp_attn(
    const float* __restrict__ q, const float* __restrict__ k_sum,
    const float* __restrict__ v_sum, const float* __restrict__ kvproj,
    float* __restrict__ out, unsigned long long* __restrict__ sel) {
  __shared__ __align__(16) float q_s[4][8][128];  // 16KB
  __shared__ __align__(16) float ks[NBc * 128];   // 31.5KB
  __shared__ float p_s[4][8][64];                 // 8KB

  const int wg = blockIdx.x;  // (b*4+kv)*128 + tq
  const int tq = wg & 127;
  const int kv = (wg >> 7) & 3;
  const int b = wg >> 9;
  const int t0 = tq * 8;
  const int tid = threadIdx.x;
  const int lane = tid & 63;
  const int g = tid >> 6;

  for (int i = tid; i < 1024; i += 256) {
    int gg = i >> 8, rem = i & 255;
    int r = rem >> 5, v = rem & 31;
    f32x4 q4 = *(const f32x4*)(q +
        (((size_t)b * NQc + gg * NKVc + kv) * Tc + t0 + r) * 128 + v * 4);
    *(f32x4*)&q_s[gg][r][v * 4] = q4;
  }
  {
    const float* kbase = k_sum + (size_t)(b * 252 + kv) * 128;
    for (int i = tid; i < NBc * 32; i += 256) {
      int n = i >> 5, s = i & 31;
      f32x4 v4 = *(const f32x4*)(kbase + (size_t)n * 512 + s * 4);
      *(f32x4*)&ks[n * 128 + ((s ^ (n & 7)) << 2)] = v4;
    }
  }
  __syncthreads();

  float acc[8] = {0.f, 0.f, 0.f, 0.f, 0.f, 0.f, 0.f, 0.f};
  {
    const int lrow = (lane < 63) ? lane : 62;
    const int lx = lrow & 7;
#pragma unroll
    for (int s = 0; s < 32; ++s) {
      f32x4 k4 = *(const f32x4*)&ks[lrow * 128 + ((s ^ lx) << 2)];
#pragma unroll
      for (int r = 0; r < 8; ++r) {
        f32x4 q4 = *(const f32x4*)&q_s[g][r][s * 4];
        acc[r] = fmaf(q4[0], k4[0], acc[r]);
        acc[r] = fmaf(q4[1], k4[1], acc[r]);
        acc[r] = fmaf(q4[2], k4[2], acc[r]);
        acc[r] = fmaf(q4[3], k4[3], acc[r]);
      }
    }
  }
#pragma unroll
  for (int r = 0; r < 8; ++r) {
    const int t = t0 + r;
    const int nvalid = min(t / STRIDEc + 1, NBc);
    const bool valid = (lane < nvalid);
    float sval = valid ? acc[r] * SCALEc : -INFINITY;
    float m = sval;
#pragma unroll
    for (int off = 32; off; off >>= 1) m = fmaxf(m, __shfl_xor(m, off));
    float e = valid ? __expf(sval - m) : 0.f;
    float l = e;
#pragma unroll
    for (int off = 32; off; off >>= 1) l += __shfl_xor(l, off);
    p_s[g][r][lane] = e / fmaxf(l, 1e-9f);
  }
  __syncthreads();

#pragma unroll
  for (int half = 0; half < 2; ++half) {
    const int rr = g + half * 4;
    float v = p_s[0][rr][lane] + p_s[1][rr][lane] + p_s[2][rr][lane] + p_s[3][rr][lane];
    if (lane >= NBc) v = -1.f;
    unsigned long long mask = 0ull;
    for (int it = 0; it < TOPNc; ++it) {
      float mx = v;
#pragma unroll
      for (int off = 32; off; off >>= 1) mx = fmaxf(mx, __shfl_xor(mx, off));
      unsigned long long ball = __ballot(v == mx);
      int sl = __ffsll(ball) - 1;
      mask |= 1ull << sl;
      if (lane == sl) v = -1.f;
    }
    if (lane == 0) sel[(((size_t)b * NKVc + kv) << 10) + t0 + rr] = mask;
  }
  {
    const float* vbase = v_sum + (size_t)(b * 252 + kv) * 128;
    for (int i = tid; i < NBc * 32; i += 256) {
      int n = i >> 5, s = i & 31;
      f32x4 v4 = *(const f32x4*)(vbase + (size_t)n * 512 + s * 4);
      *(f32x4*)&ks[n * 128 + ((s ^ (n & 7)) << 2)] = v4;
    }
  }
  __syncthreads();

  const int h = g * NKVc + kv;
  float ox[8], oy[8];
#pragma unroll
  for (int r = 0; r < 8; ++r) { ox[r] = 0.f; oy[r] = 0.f; }
  const int slotd = lane >> 1, wi = (lane & 1) * 2;
  const int nvmax = min((t0 + 7) / STRIDEc + 1, NBc);
  for (int n = 0; n < nvmax; ++n) {
    const float* vp = &ks[n * 128 + (((slotd ^ (n & 7)) << 2) | wi)];
    const float vx = vp[0], vy = vp[1];
#pragma unroll
    for (int r = 0; r < 8; ++r) {
      float pn = p_s[g][r][n];
      ox[r] = fmaf(pn, vx, ox[r]);
      oy[r] = fmaf(pn, vy, oy[r]);
    }
  }
#pragma unroll
  for (int r = 0; r < 8; ++r) {
    const int t = t0 + r;
    const float g0 = kvproj[(size_t)(b * Tc + t) * KVP_LD + 1024 + h * 3];
    size_t obase = ((size_t)(b * NQc + h) * Tc + t) * 128 + lane * 2;
    *(float2*)&out[obase] = make_float2(g0 * ox[r], g0 * oy[r]);
  }
}

// ---------- merged MFMA flash-tile attention (swapped-QK, in-register P) ----------
__global__ __launch_bounds__(512, 4) void sparse_attn_mfma(
    const float* __restrict__ q, const bf16_t* __restrict__ kvbf,
    const bf16_t* __restrict__ VT, const float* __restrict__ kvproj,
    const unsigned long long* __restrict__ sel,
    float* __restrict__ out, float* __restrict__ out2) {
  __shared__ bf16_t KsB[2][64 * 128];   // [s][d], swz ^((s&7)<<4) via pre-swz source
  __shared__ bf16_t VtB[2][128 * 64];   // [d][s], swz ^(((d>>1)&7)<<4)

  const int wgi = blockIdx.x;
  const int b = wgi & 1;
  const int kv = (wgi >> 1) & 3;
  const int Y = (wgi >> 3) & 31;
  const int mode = (wgi >> 8) & 1;
  const int tt = mode ? Y : 31 - Y;
  const int t0 = tt * 32;
  const int tid = threadIdx.x, lane = tid & 63;
  const int wv = tid >> 6;   // 0..7
  const int g = wv & 3;      // head
  const int half = wv >> 2;  // row-half
  const int t0h = t0 + half * 16;
  const int h = g * NKVc + kv;
  const int lr = lane >> 4;
  const int lc = lane & 15;
  const int tL = t0h + lc;   // this lane's softmax column (query row)

  s16x8 aq[4];
  {
    const float* qrow = q + (((size_t)(b * NQc + h) * Tc) + tL) * 128;
#pragma unroll
    for (int ks = 0; ks < 4; ++ks) {
      f32x4 lo = *(const f32x4*)(qrow + ks * 32 + lr * 8);
      f32x4 hi = *(const f32x4*)(qrow + ks * 32 + lr * 8 + 4);
      s16x8 v;
#pragma unroll
      for (int e = 0; e < 4; ++e) {
        v[e] = (short)f2bf(lo[e]);
        v[e + 4] = (short)f2bf(hi[e]);
      }
      aq[ks] = v;
    }
  }

  unsigned long long hm = ~0ull;
  unsigned long long um = ~0ull;
  int c0;
  const int c1 = (t0 + 31) >> 6;
  const unsigned long long* sb = sel + ((size_t)(b * NKVc + kv) << 10);
  if (mode == 0) {
    unsigned long long bm = sb[tL];
    hm = bm | (bm << 1);
    unsigned long long uu = 0ull;
    if (lane < 32) {
      unsigned long long b2 = sb[t0 + lane];
      uu = b2 | (b2 << 1);
    }
#pragma unroll
    for (int off = 32; off; off >>= 1) uu |= __shfl_xor(uu, off);
    um = uu;
    c0 = (__ffsll(um) - 1) >> 2;
  } else {
    int lo = t0 - (WINc - 1);
    c0 = (lo > 0 ? lo : 0) >> 6;
  }

  float run_m = -INFINITY, run_l = 0.f;
  f32x4 acc_o[8];
#pragma unroll
  for (int j = 0; j < 8; ++j) acc_o[j] = 0.f;

  const bf16_t* kb = kvbf + (mode << 10) + kv * 128;
  const bf16_t* vt = VT + (size_t)((b * 4 + kv) * 2 + mode) * 131072;
  const size_t rbase = (size_t)b * Tc;

  auto STAGE = [&](int bufi, int c) {
    const int s0 = c * 64;
#pragma unroll
    for (int p = 0; p < 2; ++p) {
      int o = p * 512 + tid;
      int s = o >> 4, sl = o & 15;
      int slot = sl ^ (s & 7);
      load_lds16(kb + (rbase + s0 + s) * KVB_LD + slot * 8,
                 (char*)&KsB[bufi][0] + (p * 512 + wv * 64) * 16);
    }
#pragma unroll
    for (int p = 0; p < 2; ++p) {
      int o = p * 512 + tid;
      int d = o >> 3, sl = o & 7;
      int slot = sl ^ ((d >> 1) & 7);
      load_lds16(vt + (size_t)d * 1024 + s0 + slot * 8,
                 (char*)&VtB[bufi][0] + (p * 512 + wv * 64) * 16);
    }
  };

  int c = c0;
  STAGE(0, c);
  int buf = 0;
  while (true) {
    int cn = c + 1;
    if (mode == 0)
      while (cn <= c1 && ((um >> (4 * cn)) & 0xFull) == 0ull) ++cn;
    __syncthreads();
    if (cn <= c1) STAGE(buf ^ 1, cn);

    const int s0 = c * 64;
    const char* KsP = (const char*)&KsB[buf][0];
    const char* VtP = (const char*)&VtB[buf][0];

    f32x4 accs[4];
#pragma unroll
    for (int j = 0; j < 4; ++j) accs[j] = 0.f;
    __builtin_amdgcn_s_setprio(1);
#pragma unroll
    for (int ks = 0; ks < 4; ++ks) {
      s16x8 bk[4];
#pragma unroll
      for (int j = 0; j < 4; ++j) {
        int sB = j * 16 + lc;
        bk[j] = *(const s16x8*)(KsP +
                                ((sB * 256 + (ks * 4 + lr) * 16) ^ ((sB & 7) << 4)));
      }
#pragma unroll
      for (int j = 0; j < 4; ++j)
        accs[j] = __builtin_amdgcn_mfma_f32_16x16x32_bf16(bk[j], aq[ks], accs[j], 0, 0, 0);
    }
    __builtin_amdgcn_s_setprio(0);

    float ev[4][4];
    float mx = -INFINITY;
#pragma unroll
    for (int j = 0; j < 4; ++j)
#pragma unroll
      for (int r = 0; r < 4; ++r) {
        int s = s0 + j * 16 + lr * 4 + r;
        bool att;
        if (mode == 0) att = (s <= tL) && ((hm >> (s >> 4)) & 1ull);
        else att = (s <= tL) && (tL - s < WINc);
        float sv = att ? accs[j][r] * SCALEc : -INFINITY;
        ev[j][r] = sv;
        mx = fmaxf(mx, sv);
      }
    mx = fmaxf(mx, __shfl_xor(mx, 16));
    mx = fmaxf(mx, __shfl_xor(mx, 32));
    const bool defer = __all(mx <= run_m + 8.f);
    float nm = run_m;
    if (!defer) {
      nm = fmaxf(run_m, mx);
      const float resc = (run_m == -INFINITY) ? 0.f : __expf(run_m - nm);
      float rs[4];
#pragma unroll
      for (int r = 0; r < 4; ++r) rs[r] = __shfl(resc, lr * 16 + lr * 4 + r);
#pragma unroll
      for (int jo = 0; jo < 8; ++jo)
#pragma unroll
        for (int r = 0; r < 4; ++r) acc_o[jo][r] *= rs[r];
      run_l *= resc;
      run_m = nm;
    }
    float cl = 0.f;
#pragma unroll
    for (int j = 0; j < 4; ++j)
#pragma unroll
      for (int r = 0; r < 4; ++r) {
        float e = (ev[j][r] == -INFINITY) ? 0.f : __expf(ev[j][r] - nm);
        ev[j][r] = e;
        cl += e;
      }
    cl += __shfl_xor(cl, 16);
    cl += __shfl_xor(cl, 32);
    run_l += cl;

    unsigned int pw[4][2];
#pragma unroll
    for (int j = 0; j < 4; ++j) {
      pw[j][0] = ((unsigned int)f2bf(ev[j][1]) << 16) | f2bf(ev[j][0]);
      pw[j][1] = ((unsigned int)f2bf(ev[j][3]) << 16) | f2bf(ev[j][2]);
    }

    s16x8 ap[2];
#pragma unroll
    for (int k2 = 0; k2 < 2; ++k2) {
      u32x4 words;
#pragma unroll
      for (int w = 0; w < 4; ++w) {
        int src = ((lr & 1) * 2 + (w >> 1)) * 16 + lc;
        unsigned int a0 = __shfl((int)pw[2 * k2][w & 1], src);
        unsigned int a1 = __shfl((int)pw[2 * k2 + 1][w & 1], src);
        words[w] = (lr >> 1) ? a1 : a0;
      }
      ap[k2] = __builtin_bit_cast(s16x8, words);
    }

    __builtin_amdgcn_s_setprio(1);
#pragma unroll
    for (int k2 = 0; k2 < 2; ++k2) {
#pragma unroll
      for (int jo = 0; jo < 8; ++jo) {
        int d = jo * 16 + lc;
        s16x8 bv = *(const s16x8*)(VtP +
                                   ((d * 128 + k2 * 64 + lr * 16) ^ (((d >> 1) & 7) << 4)));
        acc_o[jo] = __builtin_amdgcn_mfma_f32_16x16x32_bf16(ap[k2], bv, acc_o[jo], 0, 0, 0);
      }
    }
    __builtin_amdgcn_s_setprio(0);

    if (cn > c1) break;
    buf ^= 1;
    c = cn;
  }

  float rl[4];
#pragma unroll
  for (int r = 0; r < 4; ++r) rl[r] = __shfl(run_l, lr * 16 + lr * 4 + r);
#pragma unroll
  for (int r = 0; r < 4; ++r) {
    const int t = t0h + lr * 4 + r;
    const float gg = kvproj[(rbase + t) * KVP_LD + 1024 + h * 3 + 1 + mode];
    const float sc = gg / fmaxf(rl[r], 1e-9f);
    const size_t ob = ((size_t)(b * NQc + h) * Tc + t) * 128;
#pragma unroll
    for (int jo = 0; jo < 8; ++jo) {
      size_t oi = ob + jo * 16 + lc;
      float v = acc_o[jo][r] * sc;
      if (mode == 0) out[oi] += v;
      else out2[oi] = v;
    }
  }
}

// ---------- out += out2 (float4) ----------
__global__ void add_out(float* __restrict__ out, const float* __restrict__ out2) {
  size_t i = (size_t)blockIdx.x * 256 + threadIdx.x;  // exact: 1048576/256 = 4096
  f32x4 a = ((const f32x4*)out)[i];
  f32x4 bv = ((const f32x4*)out2)[i];
  ((f32x4*)out)[i] = a + bv;
}

extern "C" void kernel_launch(void* const* d_in, const int* in_sizes, int n_in,
                              void* d_out, int out_size, void* d_ws, size_t ws_size,
                              hipStream_t stream) {
  const float* x = (const float*)d_in[0];
  const float* q = (const float*)d_in[1];
  const float* gate_w = (const float*)d_in[2];
  const float* gate_b = (const float*)d_in[3];
  const float* wk_cmp = (const float*)d_in[4];
  const float* wv_cmp = (const float*)d_in[5];
  const float* wk_slc = (const float*)d_in[6];
  const float* wv_slc = (const float*)d_in[7];
  const float* wk_win = (const float*)d_in[8];
  const float* wv_win = (const float*)d_in[9];
  const float* block_pos = (const float*)d_in[10];
  const float* ck1_w = (const float*)d_in[11];
  const float* ck1_b = (const float*)d_in[12];
  const float* ck2_w = (const float*)d_in[13];
  const float* ck2_b = (const float*)d_in[14];
  const float* cv1_w = (const float*)d_in[15];
  const float* cv1_b = (const float*)d_in[16];
  const float* cv2_w = (const float*)d_in[17];
  const float* cv2_b = (const float*)d_in[18];
  float* out = (float*)d_out;

  char* wsp = (char*)d_ws;
  float* kvproj = (float*)wsp;
  bf16_t* kvbf = (bf16_t*)(wsp + 10485760);
  float* part = (float*)(wsp + 10485760);     // k_cmp partials, dead before kvbf written
  bf16_t* VT = (bf16_t*)(wsp + 18874368);
  bf16_t* xbf = (bf16_t*)(wsp + 23068672);
  bf16_t* xlo = (bf16_t*)(wsp + 31457280);
  bf16_t* Wk_hi = (bf16_t*)(wsp + 39845888);
  bf16_t* Wk_lo = (bf16_t*)(wsp + 41943040);
  bf16_t* Wcat = (bf16_t*)(wsp + 31457280);   // overwrites xlo/Wk after gemm_prec
  float* bias_cat = (float*)(wsp + 44040192);
  unsigned long long* selB = (unsigned long long*)(wsp + 44052992);
  float* hk = (float*)(wsp + 44118528);
  float* hv = (float*)(wsp + 44376576);
  float* k_sum = (float*)(wsp + 44634624);
  float* v_sum = (float*)(wsp + 44892672);
  float* bias_k = (float*)(wsp + 45150720);
  float* bias_v = (float*)(wsp + 45151232);

  float* hk_part = (float*)(wsp + 23068672);  // xbf region (dead after GEMMs)
  float* hv_part = (float*)(wsp + 27197440);
  float* out2 = (float*)(wsp + 23068672);     // 16 MB (parts/Wcat dead by then)

  dim3 blk256(256);

  prep_kernel<<<5120, blk256, 0, stream>>>(x, xbf, xlo, wk_cmp, Wk_hi, Wk_lo);

  gemm_prec<<<dim3(8, 16, 2), blk256, 0, stream>>>(xbf, xlo, Wk_hi, Wk_lo, part);
  rope_k_fused2<<<Bc * Tc * NKVc, 64, 0, stream>>>(part, kvproj);

  build_wcat<<<21504, blk256, 0, stream>>>(wv_cmp, wk_slc, wv_slc, wk_win,
                                           wv_win, gate_w, gate_b, Wcat, bias_cat);
  gemm_mfma<<<dim3(42, 16), blk256, 0, stream>>>(
      xbf, 2048, Wcat, 2048, kvproj, kvbf, VT, bias_cat, 2048);

  rope_bf<<<dim3(Bc * Tc * NKVc, 2), 64, 0, stream>>>(kvbf);

  bias_adj_kernel<<<dim3(128, 2), blk256, 0, stream>>>(block_pos, ck1_w, ck1_b,
                                                       cv1_w, cv1_b, bias_k, bias_v);
  gemm_cmp1<<<dim3(2, 8, 32), blk256, 0, stream>>>(kvproj, ck1_w, cv1_w,
                                                   hk_part, hv_part);
  reduce_gelu<<<504, blk256, 0, stream>>>(hk_part, hv_part, bias_k, bias_v, hk, hv);
  gemm_l2<<<dim3(2, 8, 2), blk256, 0, stream>>>(hk, ck2_w, ck2_b, hv, cv2_w,
                                                cv2_b, k_sum, v_sum);

  cmp_attn<<<1024, blk256, 0, stream>>>(q, k_sum, v_sum, kvproj, out, selB);
  sparse_attn_mfma<<<512, dim3(512), 0, stream>>>(q, kvbf, VT, kvproj, selB, out, out2);
  add_out<<<4096, blk256, 0, stream>>>(out, out2);
}